// Round 14
// baseline (633.087 us; speedup 1.0000x reference)
//
#include <hip/hip_runtime.h>

#define Nn 10000
#define Ee 160000
#define HID 256
#define EDIM 9
#define INDIM 10
#define Tt 5

typedef _Float16 f16;
typedef _Float16 f16x8 __attribute__((ext_vector_type(8)));
typedef _Float16 f16x4 __attribute__((ext_vector_type(4)));
typedef float f32x4 __attribute__((ext_vector_type(4)));

// ---------------- edge-attr column stats (mean / sumsq) ----------------
__global__ __launch_bounds__(256) void colstats_kernel(const float* __restrict__ in,
                                                       float* __restrict__ cs) {
  float s[9], s2[9];
#pragma unroll
  for (int k = 0; k < 9; ++k) { s[k] = 0.f; s2[k] = 0.f; }
  for (int i = blockIdx.x * blockDim.x + threadIdx.x; i < Ee; i += gridDim.x * blockDim.x) {
#pragma unroll
    for (int k = 0; k < 9; ++k) {
      float v = in[i * 9 + k];
      s[k] += v; s2[k] += v * v;
    }
  }
#pragma unroll
  for (int k = 0; k < 9; ++k) {
    for (int off = 1; off < 64; off <<= 1) {
      s[k] += __shfl_xor(s[k], off);
      s2[k] += __shfl_xor(s2[k], off);
    }
  }
  if ((threadIdx.x & 63) == 0) {
#pragma unroll
    for (int k = 0; k < 9; ++k) {
      atomicAdd(&cs[k], s[k]);
      atomicAdd(&cs[16 + k], s2[k]);
    }
  }
}

// ---------------- lift: h = relu(x @ lift_W + b), stored fp16 ----------------
__global__ __launch_bounds__(256) void lift_kernel(const float* __restrict__ x,
                                                   const float* __restrict__ W,
                                                   const float* __restrict__ b,
                                                   f16* __restrict__ hq) {
  __shared__ float xs[INDIM];
  int n = blockIdx.x, ch = threadIdx.x;
  if (ch < INDIM) xs[ch] = x[n * INDIM + ch];
  __syncthreads();
  float s = b[ch];
#pragma unroll
  for (int k = 0; k < INDIM; ++k) s += xs[k] * W[k * 256 + ch];
  hq[n * 256 + ch] = (f16)fmaxf(s, 0.f);
}

// ---------------- CSR build (by destination) ----------------
__global__ __launch_bounds__(256) void degree_kernel(const int* __restrict__ dst,
                                                     int* __restrict__ deg) {
  int e = blockIdx.x * 256 + threadIdx.x;
  if (e < Ee) atomicAdd(&deg[dst[e]], 1);
}

__global__ __launch_bounds__(1024) void scan_kernel(const int* __restrict__ deg,
                                                    int* __restrict__ rowptr,
                                                    int* __restrict__ cursor) {
  __shared__ int part[1024];
  int tid = threadIdx.x;
  const int CH = (Nn + 1023) / 1024;
  int start = tid * CH;
  int s = 0;
  for (int i = 0; i < CH; ++i) { int idx = start + i; if (idx < Nn) s += deg[idx]; }
  part[tid] = s;
  __syncthreads();
  for (int off = 1; off < 1024; off <<= 1) {
    int v = part[tid];
    int w = (tid >= off) ? part[tid - off] : 0;
    __syncthreads();
    part[tid] = v + w;
    __syncthreads();
  }
  int run = part[tid] - s;  // exclusive prefix
  for (int i = 0; i < CH; ++i) {
    int idx = start + i;
    if (idx < Nn) { rowptr[idx] = run; cursor[idx] = run; run += deg[idx]; }
  }
  if (tid == 0) rowptr[Nn] = Ee;
}

__global__ __launch_bounds__(256) void fill_kernel(const int* __restrict__ dst,
                                                   int* __restrict__ cursor,
                                                   int* __restrict__ perm) {
  int e = blockIdx.x * 256 + threadIdx.x;
  if (e < Ee) {
    int pos = atomicAdd(&cursor[dst[e]], 1);
    perm[pos] = e;
  }
}

// -------- permute src + normalized edge-attr into CSR order (stride 12) ------
__global__ __launch_bounds__(256) void eaperm_kernel(const float* __restrict__ edge_attr,
                                                     const float* __restrict__ cs,
                                                     const int* __restrict__ perm,
                                                     const int* __restrict__ srcIn,
                                                     int* __restrict__ srcp,
                                                     float* __restrict__ eap) {
  int idx = blockIdx.x * 256 + threadIdx.x;
  if (idx >= Ee) return;
  int e = perm[idx];
  srcp[idx] = srcIn[e];
  const float* a = edge_attr + e * 9;
  float o[12];
#pragma unroll
  for (int k = 0; k < 9; ++k) {
    float mu = cs[k] * (1.f / Ee);
    float var = fmaxf(cs[16 + k] * (1.f / Ee) - mu * mu, 0.f);
    o[k] = (a[k] - mu) / (sqrtf(var) + 1e-8f);
  }
  o[9] = o[10] = o[11] = 0.f;
  float4 v0 = {o[0], o[1], o[2], o[3]};
  float4 v1 = {o[4], o[5], o[6], o[7]};
  float4 v2 = {o[8], o[9], o[10], o[11]};
  *(float4*)(eap + (size_t)idx * 12 + 0) = v0;
  *(float4*)(eap + (size_t)idx * 12 + 4) = v1;
  *(float4*)(eap + (size_t)idx * 12 + 8) = v2;
}

// ---------------- weight convert: fp32 [256k,256n] -> fp16 transposed ----------------
__global__ __launch_bounds__(256) void convert_kernel(const float* __restrict__ Wl,
                                                      const float* __restrict__ Wr,
                                                      const float* __restrict__ p1,
                                                      const float* __restrict__ p2,
                                                      f16* __restrict__ wt) {
  int nrow = blockIdx.x, s = blockIdx.y, k = threadIdx.x;
  const float* srcp; int n = nrow; size_t dst;
  if (s < 5) {
    dst = (size_t)s * 131072 + (size_t)nrow * 256 + k;
    if (nrow < 256) srcp = Wl + s * 65536;
    else { srcp = Wr + s * 65536; n = nrow - 256; }
  } else {
    if (nrow >= 256) return;
    dst = 655360 + (size_t)(s - 5) * 65536 + (size_t)nrow * 256 + k;
    srcp = (s == 5) ? p1 : p2;
  }
  wt[dst] = (f16)srcp[k * 256 + n];
}

__global__ __launch_bounds__(256) void prep_bias_kernel(const float* __restrict__ bl,
                                                        const float* __restrict__ br,
                                                        float* __restrict__ bc) {
  int idx = blockIdx.x * 256 + threadIdx.x;  // 2560
  if (idx >= 2560) return;
  int t = idx >> 9, c = idx & 511;
  bc[idx] = (c < 256) ? bl[t * 256 + c] : br[t * 256 + c - 256];
}

// ------------- fp16 MFMA GEMM: A staged in LDS, B streamed from L2 -------------
__global__ __launch_bounds__(256) void gemm16_kernel(const f16* __restrict__ A,
                                                     const f16* __restrict__ BT,
                                                     const float* __restrict__ bias,
                                                     const float* __restrict__ sums,
                                                     const float* __restrict__ gamma,
                                                     const float* __restrict__ beta,
                                                     int act,
                                                     f16* __restrict__ out,
                                                     int M, int OS) {
  __shared__ __align__(16) f16 As[64][264];
  const int tid = threadIdx.x;
  const int wave = tid >> 6, lane = tid & 63;
  const int l15 = lane & 15, quad = lane >> 4;
  const int m0 = blockIdx.y * 64, n0 = blockIdx.x * 64;
  const int wm = (wave >> 1) * 32, wn = (wave & 1) * 32;
  const int colbase = (tid & 31) * 8, rowbase = tid >> 5;
  float sA[8], tA[8];
  if (act >= 0) {
#pragma unroll
    for (int c4 = 0; c4 < 2; ++c4) {
      float su_[4] = {0.f, 0.f, 0.f, 0.f}, sq_[4] = {0.f, 0.f, 0.f, 0.f};
#pragma unroll
      for (int p = 0; p < 8; ++p) {
        float4 su = *(const float4*)(sums + p * 512 + colbase + c4 * 4);
        float4 sq = *(const float4*)(sums + p * 512 + 256 + colbase + c4 * 4);
        su_[0] += su.x; su_[1] += su.y; su_[2] += su.z; su_[3] += su.w;
        sq_[0] += sq.x; sq_[1] += sq.y; sq_[2] += sq.z; sq_[3] += sq.w;
      }
      float4 g4 = *(const float4*)(gamma + colbase + c4 * 4);
      float4 b4 = *(const float4*)(beta + colbase + c4 * 4);
      float g_[4] = {g4.x, g4.y, g4.z, g4.w};
      float b_[4] = {b4.x, b4.y, b4.z, b4.w};
#pragma unroll
      for (int c = 0; c < 4; ++c) {
        float mu = su_[c] * (1.f / Nn);
        float var = fmaxf(sq_[c] * (1.f / Nn) - mu * mu, 0.f);
        float is = rsqrtf(var + 1e-5f) * g_[c];
        sA[c4 * 4 + c] = is;
        tA[c4 * 4 + c] = b_[c] - mu * is;
      }
    }
  }
  // stage A panel (64x256) only: 8 x 16B chunks per thread
#pragma unroll
  for (int i = 0; i < 8; ++i) {
    int c = tid + 256 * i;
    int row = c >> 5, col = (c & 31) * 8;
    f16x8 av = {};
    int gm = m0 + row;
    if (gm < M) av = *(const f16x8*)(A + (size_t)gm * 256 + col);
    if (act >= 0) {
#pragma unroll
      for (int e = 0; e < 8; ++e) {
        float y = (float)av[e] * sA[e] + tA[e];
        if (act == 0) y = y > 0.f ? y : (__expf(y) - 1.f);
        else y = fmaxf(y, 0.f);
        av[e] = (f16)y;
      }
    }
    *(f16x8*)(&As[row][col]) = av;
  }
  __syncthreads();
  const f16* pb0 = BT + (size_t)(n0 + wn + l15) * 256 + quad * 8;
  const f16* pb1 = BT + (size_t)(n0 + wn + 16 + l15) * 256 + quad * 8;
  f32x4 zero4 = {0.f, 0.f, 0.f, 0.f};
  f32x4 acc[2][2] = {{zero4, zero4}, {zero4, zero4}};
#pragma unroll
  for (int kk = 0; kk < 256; kk += 32) {
    f16x8 a0 = *(const f16x8*)(&As[wm + l15][kk + quad * 8]);
    f16x8 a1 = *(const f16x8*)(&As[wm + 16 + l15][kk + quad * 8]);
    f16x8 b0 = *(const f16x8*)(pb0 + kk);
    f16x8 b1 = *(const f16x8*)(pb1 + kk);
    acc[0][0] = __builtin_amdgcn_mfma_f32_16x16x32_f16(a0, b0, acc[0][0], 0, 0, 0);
    acc[0][1] = __builtin_amdgcn_mfma_f32_16x16x32_f16(a0, b1, acc[0][1], 0, 0, 0);
    acc[1][0] = __builtin_amdgcn_mfma_f32_16x16x32_f16(a1, b0, acc[1][0], 0, 0, 0);
    acc[1][1] = __builtin_amdgcn_mfma_f32_16x16x32_f16(a1, b1, acc[1][1], 0, 0, 0);
  }
  // epilogue: bias add, fp16 via LDS transpose for coalesced 16B stores
  __syncthreads();
  f16* Cs = (f16*)&As[0][0];  // 64 x 72 tile (reuses As)
#pragma unroll
  for (int ni = 0; ni < 2; ++ni) {
    int nl = wn + ni * 16 + l15;
    float bv = bias[n0 + nl];
#pragma unroll
    for (int mi = 0; mi < 2; ++mi)
#pragma unroll
      for (int r = 0; r < 4; ++r)
        Cs[(wm + mi * 16 + quad * 4 + r) * 72 + nl] = (f16)(acc[mi][ni][r] + bv);
  }
  __syncthreads();
  {
    int row = tid >> 2, c4 = (tid & 3) * 16;
    int gm = m0 + row;
    if (gm < M) {
      f16x8 v0 = *(const f16x8*)(&Cs[row * 72 + c4]);
      f16x8 v1 = *(const f16x8*)(&Cs[row * 72 + c4 + 8]);
      *(f16x8*)(out + (size_t)gm * OS + n0 + c4) = v0;
      *(f16x8*)(out + (size_t)gm * OS + n0 + c4 + 8) = v1;
    }
  }
}

// ---- Fused GATv2 + BN stats: wave/node, batch-4, 2-deep software pipeline ----
// Prefetch js two batches ahead and xl rows one batch ahead so both levels of
// the dependent load chain (srcp -> hxlr row) are in flight a full iteration
// before use. Compute consumes registers loaded last iteration.
__global__ __launch_bounds__(256) void gat_fused(const f16* __restrict__ hxlr,
                                                 const float* __restrict__ eap,
                                                 const int* __restrict__ srcp,
                                                 const int* __restrict__ rowptr,
                                                 const float* __restrict__ We_t,
                                                 const float* __restrict__ att_t,
                                                 const float* __restrict__ cb_t,
                                                 f16* __restrict__ outb,
                                                 float* __restrict__ bns) {
  __shared__ float ls[2048];  // [wave][sum 256 | sumsq 256]
  int wave = threadIdx.x >> 6, lane = threadIdx.x & 63;
  int i = blockIdx.x * 4 + wave;  // 2500 * 4 == Nn exactly
  int ch = lane * 4;  // lane owns flat channels [ch, ch+4); head = lane>>3
  float we[9][4];
#pragma unroll
  for (int k = 0; k < 9; ++k) {
    float4 w4 = *(const float4*)(We_t + k * 256 + ch);
    we[k][0] = w4.x; we[k][1] = w4.y; we[k][2] = w4.z; we[k][3] = w4.w;
  }
  float4 a4 = *(const float4*)(att_t + ch);
  float att[4] = {a4.x, a4.y, a4.z, a4.w};
  f16x4 xr4 = *(const f16x4*)(hxlr + (size_t)i * 512 + 256 + ch);
  float xri[4] = {(float)xr4[0], (float)xr4[1], (float)xr4[2], (float)xr4[3]};
  float acc[4] = {0.f, 0.f, 0.f, 0.f};
  float d = 0.f;
  int r0 = rowptr[i], r1 = rowptr[i + 1];
  if (r0 < r1) {
    const int lastb = r0 + (((r1 - r0 - 1) >> 2) << 2);  // base of last batch
    int js_c[4], js_n[4];
    f16x4 xl_c[4], xl_n[4];
    // prologue: batch0 js+xl, batch1 js
    {
      int cnt = r1 - r0;
#pragma unroll
      for (int b = 0; b < 4; ++b) js_c[b] = srcp[r0 + (b < cnt ? b : cnt - 1)];
#pragma unroll
      for (int b = 0; b < 4; ++b)
        xl_c[b] = *(const f16x4*)(hxlr + (size_t)js_c[b] * 512 + ch);
      int nb1 = r0 + 4; if (nb1 > lastb) nb1 = lastb;
      int ncnt = r1 - nb1;
#pragma unroll
      for (int b = 0; b < 4; ++b) js_n[b] = srcp[nb1 + (b < ncnt ? b : ncnt - 1)];
    }
    for (int base = r0; base < r1; base += 4) {
      // issue xl loads for batch+1 (js_n loaded an iteration ago)
#pragma unroll
      for (int b = 0; b < 4; ++b)
        xl_n[b] = *(const f16x4*)(hxlr + (size_t)js_n[b] * 512 + ch);
      // issue js loads for batch+2
      int js_n2[4];
      {
        int nb2 = base + 8; if (nb2 > lastb) nb2 = lastb;
        int ncnt = r1 - nb2;
#pragma unroll
        for (int b = 0; b < 4; ++b) js_n2[b] = srcp[nb2 + (b < ncnt ? b : ncnt - 1)];
      }
      // compute current batch from xl_c (loaded an iteration ago)
      int cnt = r1 - base;
      float xlv[4][4];
#pragma unroll
      for (int b = 0; b < 4; ++b) {
        xlv[b][0] = (float)xl_c[b][0]; xlv[b][1] = (float)xl_c[b][1];
        xlv[b][2] = (float)xl_c[b][2]; xlv[b][3] = (float)xl_c[b][3];
      }
      float sp[4];
#pragma unroll
      for (int b = 0; b < 4; ++b) {
        int bb = b < cnt ? b : cnt - 1;
        const float* ep = eap + (size_t)(base + bb) * 12;
        float4 e0 = *(const float4*)ep;
        float4 e1 = *(const float4*)(ep + 4);
        float e8 = ep[8];
        float s = 0.f;
#pragma unroll
        for (int c = 0; c < 4; ++c) {
          float v = xlv[b][c] + xri[c];
          v += e0.x * we[0][c] + e0.y * we[1][c] + e0.z * we[2][c] + e0.w * we[3][c];
          v += e1.x * we[4][c] + e1.y * we[5][c] + e1.z * we[6][c] + e1.w * we[7][c];
          v += e8 * we[8][c];
          v = v > 0.f ? v : 0.2f * v;  // leaky_relu 0.2
          s += att[c] * v;
        }
        sp[b] = s;
      }
#pragma unroll
      for (int b = 0; b < 4; ++b) {
        sp[b] += __shfl_xor(sp[b], 1);
        sp[b] += __shfl_xor(sp[b], 2);
        sp[b] += __shfl_xor(sp[b], 4);
      }
#pragma unroll
      for (int b = 0; b < 4; ++b) {
        float z = (b < cnt) ? __expf(fminf(sp[b], 75.f)) : 0.f;
        d += z;
#pragma unroll
        for (int c = 0; c < 4; ++c) acc[c] += z * xlv[b][c];
      }
      // rotate pipeline registers
#pragma unroll
      for (int b = 0; b < 4; ++b) { js_n[b] = js_n2[b]; xl_c[b] = xl_n[b]; }
    }
  }
  float inv = 1.f / (d + 1e-16f);  // empty node -> bias only (matches ref)
  float4 cb4 = *(const float4*)(cb_t + ch);
  f16x4 o;
  o[0] = (f16)(acc[0] * inv + cb4.x);
  o[1] = (f16)(acc[1] * inv + cb4.y);
  o[2] = (f16)(acc[2] * inv + cb4.z);
  o[3] = (f16)(acc[3] * inv + cb4.w);
  *(f16x4*)(outb + (size_t)i * 256 + ch) = o;
  // fused BN stats on the f16-rounded output
#pragma unroll
  for (int c = 0; c < 4; ++c) {
    float xv = (float)o[c];
    ls[wave * 512 + ch + c] = xv;
    ls[wave * 512 + 256 + ch + c] = xv * xv;
  }
  __syncthreads();
  float* bp = bns + (blockIdx.x & 7) * 512;  // 8-way partials: contention /8
  for (int q = threadIdx.x; q < 512; q += 256) {
    float sv = ls[q] + ls[512 + q] + ls[1024 + q] + ls[1536 + q];
    atomicAdd(&bp[q], sv);
  }
}

// ------ BatchNorm batch-stats (standalone, head only; writes 8-way partial) ------
__global__ __launch_bounds__(256) void bn_stats_kernel(const f16* __restrict__ v,
                                                       float* __restrict__ sums) {
  __shared__ float ls[512];
  int tid = threadIdx.x;
  for (int i = tid; i < 512; i += 256) ls[i] = 0.f;
  __syncthreads();
  int wave = tid >> 6, lane = tid & 63, ch = lane * 4;
  float s[4] = {0.f, 0.f, 0.f, 0.f}, s2[4] = {0.f, 0.f, 0.f, 0.f};
  for (int r = blockIdx.x * 4 + wave; r < Nn; r += gridDim.x * 4) {
    f16x4 x4 = *(const f16x4*)(v + (size_t)r * 256 + ch);
#pragma unroll
    for (int c = 0; c < 4; ++c) {
      float x = (float)x4[c];
      s[c] += x; s2[c] += x * x;
    }
  }
#pragma unroll
  for (int c = 0; c < 4; ++c) {
    atomicAdd(&ls[ch + c], s[c]);
    atomicAdd(&ls[256 + ch + c], s2[c]);
  }
  __syncthreads();
  float* sp2 = sums + (blockIdx.x & 7) * 512;
  for (int i = tid; i < 512; i += 256) atomicAdd(&sp2[i], ls[i]);
}

// ---------------- final: BN(pbn2)+ReLU folded, 256 -> 3 projection ----------------
__global__ __launch_bounds__(256) void final_kernel(const f16* __restrict__ hq,
                                                    const float* __restrict__ sums,
                                                    const float* __restrict__ gamma,
                                                    const float* __restrict__ beta,
                                                    const float* __restrict__ W,
                                                    const float* __restrict__ b,
                                                    float* __restrict__ out3) {
  int wave = threadIdx.x >> 6, lane = threadIdx.x & 63;
  int n = blockIdx.x * 4 + wave;
  if (n >= Nn) return;
  int ch = lane * 4;
  float su_[4] = {0.f, 0.f, 0.f, 0.f}, sq_[4] = {0.f, 0.f, 0.f, 0.f};
#pragma unroll
  for (int p = 0; p < 8; ++p) {
    float4 su = *(const float4*)(sums + p * 512 + ch);
    float4 sq = *(const float4*)(sums + p * 512 + 256 + ch);
    su_[0] += su.x; su_[1] += su.y; su_[2] += su.z; su_[3] += su.w;
    sq_[0] += sq.x; sq_[1] += sq.y; sq_[2] += sq.z; sq_[3] += sq.w;
  }
  float4 g4 = *(const float4*)(gamma + ch);
  float4 b4 = *(const float4*)(beta + ch);
  float g_[4] = {g4.x, g4.y, g4.z, g4.w};
  float bb_[4] = {b4.x, b4.y, b4.z, b4.w};
  f16x4 h4 = *(const f16x4*)(hq + (size_t)n * 256 + ch);
  float s0 = 0.f, s1 = 0.f, s2 = 0.f;
#pragma unroll
  for (int c = 0; c < 4; ++c) {
    float mu = su_[c] * (1.f / Nn);
    float var = fmaxf(sq_[c] * (1.f / Nn) - mu * mu, 0.f);
    float is = rsqrtf(var + 1e-5f) * g_[c];
    float y = fmaxf(((float)h4[c] - mu) * is + bb_[c], 0.f);
    const float* w = W + (ch + c) * 3;
    s0 += y * w[0]; s1 += y * w[1]; s2 += y * w[2];
  }
  for (int off = 1; off < 64; off <<= 1) {
    s0 += __shfl_xor(s0, off);
    s1 += __shfl_xor(s1, off);
    s2 += __shfl_xor(s2, off);
  }
  if (lane == 0) {
    out3[n * 3 + 0] = s0 + b[0];
    out3[n * 3 + 1] = s1 + b[1];
    out3[n * 3 + 2] = s2 + b[2];
  }
}

extern "C" void kernel_launch(void* const* d_in, const int* in_sizes, int n_in,
                              void* d_out, int out_size, void* d_ws, size_t ws_size,
                              hipStream_t stream) {
  const float* x         = (const float*)d_in[0];
  const float* edge_attr = (const float*)d_in[1];
  const int*   eidx      = (const int*)d_in[2];
  const float* lift_W    = (const float*)d_in[3];
  const float* lift_b    = (const float*)d_in[4];
  const float* Wl        = (const float*)d_in[5];
  const float* bl        = (const float*)d_in[6];
  const float* Wr        = (const float*)d_in[7];
  const float* br        = (const float*)d_in[8];
  const float* We        = (const float*)d_in[9];
  const float* att       = (const float*)d_in[10];
  const float* conv_b    = (const float*)d_in[11];
  const float* bn_g      = (const float*)d_in[12];
  const float* bn_b      = (const float*)d_in[13];
  const float* p1_W      = (const float*)d_in[14];
  const float* p1_b      = (const float*)d_in[15];
  const float* pbn1_g    = (const float*)d_in[16];
  const float* pbn1_b    = (const float*)d_in[17];
  const float* p2_W      = (const float*)d_in[18];
  const float* p2_b      = (const float*)d_in[19];
  const float* pbn2_g    = (const float*)d_in[20];
  const float* pbn2_b    = (const float*)d_in[21];
  const float* p3_W      = (const float*)d_in[22];
  const float* p3_b      = (const float*)d_in[23];
  const int* srcI = eidx;
  const int* dstI = eidx + Ee;

  char* wp = (char*)d_ws;
  auto carve = [&](size_t bytes) -> void* {
    void* p = (void*)wp;
    wp += (bytes + 255) & ~(size_t)255;
    return p;
  };
  // zero region: cstats(32) + bnsA(7 sets x 8 partials x 512) + deg(Nn)
  char*  zr     = (char*)carve((size_t)(32 + 7 * 4096 + Nn) * 4);
  float* cstats = (float*)zr;
  float* bnsA   = (float*)(zr + 32 * 4);
  int*   deg    = (int*)(zr + (32 + 7 * 4096) * 4);
  float* eap    = (float*)carve((size_t)Ee * 12 * sizeof(float));
  f16*   h16    = (f16*)carve((size_t)Nn * 256 * sizeof(f16));
  f16*   w16t   = (f16*)carve((size_t)786432 * sizeof(f16));
  float* biascat= (float*)carve((size_t)2560 * sizeof(float));
  f16*   hxlr   = (f16*)carve((size_t)Nn * 512 * sizeof(f16));
  f16*   outb16 = (f16*)carve((size_t)Nn * 256 * sizeof(f16));
  int*   rowptr = (int*)carve((size_t)(Nn + 1) * sizeof(int));
  int*   cursor = (int*)carve((size_t)Nn * sizeof(int));
  int*   perm   = (int*)carve((size_t)Ee * sizeof(int));
  int*   srcp   = (int*)carve((size_t)Ee * sizeof(int));

  hipMemsetAsync(zr, 0, (size_t)(32 + 7 * 4096 + Nn) * 4, stream);

  colstats_kernel<<<64, 256, 0, stream>>>(edge_attr, cstats);
  lift_kernel<<<Nn, 256, 0, stream>>>(x, lift_W, lift_b, h16);
  degree_kernel<<<(Ee + 255) / 256, 256, 0, stream>>>(dstI, deg);
  scan_kernel<<<1, 1024, 0, stream>>>(deg, rowptr, cursor);
  fill_kernel<<<(Ee + 255) / 256, 256, 0, stream>>>(dstI, cursor, perm);
  eaperm_kernel<<<(Ee + 255) / 256, 256, 0, stream>>>(edge_attr, cstats, perm, srcI, srcp, eap);
  convert_kernel<<<dim3(512, 7), 256, 0, stream>>>(Wl, Wr, p1_W, p2_W, w16t);
  prep_bias_kernel<<<10, 256, 0, stream>>>(bl, br, biascat);

  const int MB = (Nn + 63) / 64;  // 157
  for (int t = 0; t < Tt; ++t) {
    const f16* Ain = (t == 0) ? h16 : outb16;
    const float* sums = (t == 0) ? nullptr : bnsA + (size_t)(t - 1) * 4096;
    int act = (t == 0) ? -1 : 0;
    gemm16_kernel<<<dim3(8, MB), 256, 0, stream>>>(Ain, w16t + (size_t)t * 131072,
                                                   biascat + t * 512, sums,
                                                   bn_g + (t > 0 ? (t - 1) * 256 : 0),
                                                   bn_b + (t > 0 ? (t - 1) * 256 : 0),
                                                   act, hxlr, Nn, 512);
    gat_fused<<<2500, 256, 0, stream>>>(hxlr, eap, srcp, rowptr,
                                        We + t * 9 * 256, att + t * 256,
                                        conv_b + t * 256, outb16,
                                        bnsA + (size_t)t * 4096);
  }
  // projection head: p1 (BN4+ELU folded), p2 (pbn1+ReLU folded), final (pbn2+ReLU folded)
  f16* pA = hxlr;                    // Nn*256
  f16* pB = hxlr + (size_t)Nn * 256; // Nn*256
  gemm16_kernel<<<dim3(4, MB), 256, 0, stream>>>(outb16, w16t + 655360, p1_b,
                                                 bnsA + 4 * 4096, bn_g + 4 * 256, bn_b + 4 * 256,
                                                 0, pA, Nn, 256);
  bn_stats_kernel<<<128, 256, 0, stream>>>(pA, bnsA + 5 * 4096);
  gemm16_kernel<<<dim3(4, MB), 256, 0, stream>>>(pA, w16t + 720896, p2_b,
                                                 bnsA + 5 * 4096, pbn1_g, pbn1_b,
                                                 1, pB, Nn, 256);
  bn_stats_kernel<<<128, 256, 0, stream>>>(pB, bnsA + 6 * 4096);
  final_kernel<<<2500, 256, 0, stream>>>(pB, bnsA + 6 * 4096, pbn2_g, pbn2_b, p3_W, p3_b,
                                         (float*)d_out);
}

// Round 15
// 609.643 us; speedup vs baseline: 1.0385x; 1.0385x over previous
//
#include <hip/hip_runtime.h>

#define Nn 10000
#define Ee 160000
#define HID 256
#define EDIM 9
#define INDIM 10
#define Tt 5

typedef _Float16 f16;
typedef _Float16 f16x8 __attribute__((ext_vector_type(8)));
typedef _Float16 f16x4 __attribute__((ext_vector_type(4)));
typedef float f32x4 __attribute__((ext_vector_type(4)));

static __device__ __forceinline__ f16x4 splat4(f16 x) {
  f16x4 r = {x, x, x, x};
  return r;
}

// ---------------- edge-attr column stats (mean / sumsq) ----------------
__global__ __launch_bounds__(256) void colstats_kernel(const float* __restrict__ in,
                                                       float* __restrict__ cs) {
  float s[9], s2[9];
#pragma unroll
  for (int k = 0; k < 9; ++k) { s[k] = 0.f; s2[k] = 0.f; }
  for (int i = blockIdx.x * blockDim.x + threadIdx.x; i < Ee; i += gridDim.x * blockDim.x) {
#pragma unroll
    for (int k = 0; k < 9; ++k) {
      float v = in[i * 9 + k];
      s[k] += v; s2[k] += v * v;
    }
  }
#pragma unroll
  for (int k = 0; k < 9; ++k) {
    for (int off = 1; off < 64; off <<= 1) {
      s[k] += __shfl_xor(s[k], off);
      s2[k] += __shfl_xor(s2[k], off);
    }
  }
  if ((threadIdx.x & 63) == 0) {
#pragma unroll
    for (int k = 0; k < 9; ++k) {
      atomicAdd(&cs[k], s[k]);
      atomicAdd(&cs[16 + k], s2[k]);
    }
  }
}

// ---------------- lift: h = relu(x @ lift_W + b), stored fp16 ----------------
__global__ __launch_bounds__(256) void lift_kernel(const float* __restrict__ x,
                                                   const float* __restrict__ W,
                                                   const float* __restrict__ b,
                                                   f16* __restrict__ hq) {
  __shared__ float xs[INDIM];
  int n = blockIdx.x, ch = threadIdx.x;
  if (ch < INDIM) xs[ch] = x[n * INDIM + ch];
  __syncthreads();
  float s = b[ch];
#pragma unroll
  for (int k = 0; k < INDIM; ++k) s += xs[k] * W[k * 256 + ch];
  hq[n * 256 + ch] = (f16)fmaxf(s, 0.f);
}

// ---------------- CSR build (by destination) ----------------
__global__ __launch_bounds__(256) void degree_kernel(const int* __restrict__ dst,
                                                     int* __restrict__ deg) {
  int e = blockIdx.x * 256 + threadIdx.x;
  if (e < Ee) atomicAdd(&deg[dst[e]], 1);
}

__global__ __launch_bounds__(1024) void scan_kernel(const int* __restrict__ deg,
                                                    int* __restrict__ rowptr,
                                                    int* __restrict__ cursor) {
  __shared__ int part[1024];
  int tid = threadIdx.x;
  const int CH = (Nn + 1023) / 1024;
  int start = tid * CH;
  int s = 0;
  for (int i = 0; i < CH; ++i) { int idx = start + i; if (idx < Nn) s += deg[idx]; }
  part[tid] = s;
  __syncthreads();
  for (int off = 1; off < 1024; off <<= 1) {
    int v = part[tid];
    int w = (tid >= off) ? part[tid - off] : 0;
    __syncthreads();
    part[tid] = v + w;
    __syncthreads();
  }
  int run = part[tid] - s;  // exclusive prefix
  for (int i = 0; i < CH; ++i) {
    int idx = start + i;
    if (idx < Nn) { rowptr[idx] = run; cursor[idx] = run; run += deg[idx]; }
  }
  if (tid == 0) rowptr[Nn] = Ee;
}

__global__ __launch_bounds__(256) void fill_kernel(const int* __restrict__ dst,
                                                   int* __restrict__ cursor,
                                                   int* __restrict__ perm) {
  int e = blockIdx.x * 256 + threadIdx.x;
  if (e < Ee) {
    int pos = atomicAdd(&cursor[dst[e]], 1);
    perm[pos] = e;
  }
}

// -- permute src + normalized edge-attr into CSR order, f16 stride 16 --
__global__ __launch_bounds__(256) void eaperm_kernel(const float* __restrict__ edge_attr,
                                                     const float* __restrict__ cs,
                                                     const int* __restrict__ perm,
                                                     const int* __restrict__ srcIn,
                                                     int* __restrict__ srcp,
                                                     f16* __restrict__ eap16) {
  int idx = blockIdx.x * 256 + threadIdx.x;
  if (idx >= Ee) return;
  int e = perm[idx];
  srcp[idx] = srcIn[e];
  const float* a = edge_attr + e * 9;
  f16 o[16];
#pragma unroll
  for (int k = 0; k < 9; ++k) {
    float mu = cs[k] * (1.f / Ee);
    float var = fmaxf(cs[16 + k] * (1.f / Ee) - mu * mu, 0.f);
    o[k] = (f16)((a[k] - mu) / (sqrtf(var) + 1e-8f));
  }
#pragma unroll
  for (int k = 9; k < 16; ++k) o[k] = (f16)0.f;
  f16x8 v0, v1;
#pragma unroll
  for (int k = 0; k < 8; ++k) { v0[k] = o[k]; v1[k] = o[8 + k]; }
  *(f16x8*)(eap16 + (size_t)idx * 16) = v0;
  *(f16x8*)(eap16 + (size_t)idx * 16 + 8) = v1;
}

// ---------------- weight convert: fp32 [256k,256n] -> fp16 transposed ----------------
__global__ __launch_bounds__(256) void convert_kernel(const float* __restrict__ Wl,
                                                      const float* __restrict__ Wr,
                                                      const float* __restrict__ p1,
                                                      const float* __restrict__ p2,
                                                      f16* __restrict__ wt) {
  int nrow = blockIdx.x, s = blockIdx.y, k = threadIdx.x;
  const float* srcp; int n = nrow; size_t dst;
  if (s < 5) {
    dst = (size_t)s * 131072 + (size_t)nrow * 256 + k;
    if (nrow < 256) srcp = Wl + s * 65536;
    else { srcp = Wr + s * 65536; n = nrow - 256; }
  } else {
    if (nrow >= 256) return;
    dst = 655360 + (size_t)(s - 5) * 65536 + (size_t)nrow * 256 + k;
    srcp = (s == 5) ? p1 : p2;
  }
  wt[dst] = (f16)srcp[k * 256 + n];
}

__global__ __launch_bounds__(256) void prep_bias_kernel(const float* __restrict__ bl,
                                                        const float* __restrict__ br,
                                                        float* __restrict__ bc) {
  int idx = blockIdx.x * 256 + threadIdx.x;  // 2560
  if (idx >= 2560) return;
  int t = idx >> 9, c = idx & 511;
  bc[idx] = (c < 256) ? bl[t * 256 + c] : br[t * 256 + c - 256];
}

// ------------- fp16 MFMA GEMM: A staged in LDS, B streamed from L2 -------------
__global__ __launch_bounds__(256) void gemm16_kernel(const f16* __restrict__ A,
                                                     const f16* __restrict__ BT,
                                                     const float* __restrict__ bias,
                                                     const float* __restrict__ sums,
                                                     const float* __restrict__ gamma,
                                                     const float* __restrict__ beta,
                                                     int act,
                                                     f16* __restrict__ out,
                                                     int M, int OS) {
  __shared__ __align__(16) f16 As[64][264];
  const int tid = threadIdx.x;
  const int wave = tid >> 6, lane = tid & 63;
  const int l15 = lane & 15, quad = lane >> 4;
  const int m0 = blockIdx.y * 64, n0 = blockIdx.x * 64;
  const int wm = (wave >> 1) * 32, wn = (wave & 1) * 32;
  const int colbase = (tid & 31) * 8, rowbase = tid >> 5;
  float sA[8], tA[8];
  if (act >= 0) {
#pragma unroll
    for (int c4 = 0; c4 < 2; ++c4) {
      float su_[4] = {0.f, 0.f, 0.f, 0.f}, sq_[4] = {0.f, 0.f, 0.f, 0.f};
#pragma unroll
      for (int p = 0; p < 8; ++p) {
        float4 su = *(const float4*)(sums + p * 512 + colbase + c4 * 4);
        float4 sq = *(const float4*)(sums + p * 512 + 256 + colbase + c4 * 4);
        su_[0] += su.x; su_[1] += su.y; su_[2] += su.z; su_[3] += su.w;
        sq_[0] += sq.x; sq_[1] += sq.y; sq_[2] += sq.z; sq_[3] += sq.w;
      }
      float4 g4 = *(const float4*)(gamma + colbase + c4 * 4);
      float4 b4 = *(const float4*)(beta + colbase + c4 * 4);
      float g_[4] = {g4.x, g4.y, g4.z, g4.w};
      float b_[4] = {b4.x, b4.y, b4.z, b4.w};
#pragma unroll
      for (int c = 0; c < 4; ++c) {
        float mu = su_[c] * (1.f / Nn);
        float var = fmaxf(sq_[c] * (1.f / Nn) - mu * mu, 0.f);
        float is = rsqrtf(var + 1e-5f) * g_[c];
        sA[c4 * 4 + c] = is;
        tA[c4 * 4 + c] = b_[c] - mu * is;
      }
    }
  }
  // stage A panel (64x256) only: 8 x 16B chunks per thread
#pragma unroll
  for (int i = 0; i < 8; ++i) {
    int c = tid + 256 * i;
    int row = c >> 5, col = (c & 31) * 8;
    f16x8 av = {};
    int gm = m0 + row;
    if (gm < M) av = *(const f16x8*)(A + (size_t)gm * 256 + col);
    if (act >= 0) {
#pragma unroll
      for (int e = 0; e < 8; ++e) {
        float y = (float)av[e] * sA[e] + tA[e];
        if (act == 0) y = y > 0.f ? y : (__expf(y) - 1.f);
        else y = fmaxf(y, 0.f);
        av[e] = (f16)y;
      }
    }
    *(f16x8*)(&As[row][col]) = av;
  }
  __syncthreads();
  const f16* pb0 = BT + (size_t)(n0 + wn + l15) * 256 + quad * 8;
  const f16* pb1 = BT + (size_t)(n0 + wn + 16 + l15) * 256 + quad * 8;
  f32x4 zero4 = {0.f, 0.f, 0.f, 0.f};
  f32x4 acc[2][2] = {{zero4, zero4}, {zero4, zero4}};
#pragma unroll
  for (int kk = 0; kk < 256; kk += 32) {
    f16x8 a0 = *(const f16x8*)(&As[wm + l15][kk + quad * 8]);
    f16x8 a1 = *(const f16x8*)(&As[wm + 16 + l15][kk + quad * 8]);
    f16x8 b0 = *(const f16x8*)(pb0 + kk);
    f16x8 b1 = *(const f16x8*)(pb1 + kk);
    acc[0][0] = __builtin_amdgcn_mfma_f32_16x16x32_f16(a0, b0, acc[0][0], 0, 0, 0);
    acc[0][1] = __builtin_amdgcn_mfma_f32_16x16x32_f16(a0, b1, acc[0][1], 0, 0, 0);
    acc[1][0] = __builtin_amdgcn_mfma_f32_16x16x32_f16(a1, b0, acc[1][0], 0, 0, 0);
    acc[1][1] = __builtin_amdgcn_mfma_f32_16x16x32_f16(a1, b1, acc[1][1], 0, 0, 0);
  }
  // epilogue: bias add, fp16 via LDS transpose for coalesced 16B stores
  __syncthreads();
  f16* Cs = (f16*)&As[0][0];  // 64 x 72 tile (reuses As)
#pragma unroll
  for (int ni = 0; ni < 2; ++ni) {
    int nl = wn + ni * 16 + l15;
    float bv = bias[n0 + nl];
#pragma unroll
    for (int mi = 0; mi < 2; ++mi)
#pragma unroll
      for (int r = 0; r < 4; ++r)
        Cs[(wm + mi * 16 + quad * 4 + r) * 72 + nl] = (f16)(acc[mi][ni][r] + bv);
  }
  __syncthreads();
  {
    int row = tid >> 2, c4 = (tid & 3) * 16;
    int gm = m0 + row;
    if (gm < M) {
      f16x8 v0 = *(const f16x8*)(&Cs[row * 72 + c4]);
      f16x8 v1 = *(const f16x8*)(&Cs[row * 72 + c4 + 8]);
      *(f16x8*)(out + (size_t)gm * OS + n0 + c4) = v0;
      *(f16x8*)(out + (size_t)gm * OS + n0 + c4 + 8) = v1;
    }
  }
}

// ---- Fused GATv2 + BN stats: wave/node, batch-4, packed-f16 edge MLP ----
// MLP accumulates in f16x4 (v_pk_add/fma_f16: half the VALU insts of f32);
// lrelu/att-dot/softmax/acc stay f32. eap stored f16 stride-16.
__global__ __launch_bounds__(256) void gat_fused(const f16* __restrict__ hxlr,
                                                 const f16* __restrict__ eap16,
                                                 const int* __restrict__ srcp,
                                                 const int* __restrict__ rowptr,
                                                 const float* __restrict__ We_t,
                                                 const float* __restrict__ att_t,
                                                 const float* __restrict__ cb_t,
                                                 f16* __restrict__ outb,
                                                 float* __restrict__ bns) {
  __shared__ float ls[2048];  // [wave][sum 256 | sumsq 256]
  int wave = threadIdx.x >> 6, lane = threadIdx.x & 63;
  int i = blockIdx.x * 4 + wave;  // 2500 * 4 == Nn exactly
  int ch = lane * 4;  // lane owns flat channels [ch, ch+4); head = lane>>3
  f16x4 we16[9];
#pragma unroll
  for (int k = 0; k < 9; ++k) {
    float4 w4 = *(const float4*)(We_t + k * 256 + ch);
    we16[k][0] = (f16)w4.x; we16[k][1] = (f16)w4.y;
    we16[k][2] = (f16)w4.z; we16[k][3] = (f16)w4.w;
  }
  float4 a4 = *(const float4*)(att_t + ch);
  float att[4] = {a4.x, a4.y, a4.z, a4.w};
  f16x4 xr16 = *(const f16x4*)(hxlr + (size_t)i * 512 + 256 + ch);
  float acc[4] = {0.f, 0.f, 0.f, 0.f};
  float d = 0.f;
  int r0 = rowptr[i], r1 = rowptr[i + 1];
  for (int base = r0; base < r1; base += 4) {
    int cnt = r1 - base;  // >= 1
    int ib[4];
#pragma unroll
    for (int b = 0; b < 4; ++b) ib[b] = base + (b < cnt ? b : cnt - 1);
    int js[4];
#pragma unroll
    for (int b = 0; b < 4; ++b) js[b] = srcp[ib[b]];
    f16x4 xl4[4];
#pragma unroll
    for (int b = 0; b < 4; ++b)
      xl4[b] = *(const f16x4*)(hxlr + (size_t)js[b] * 512 + ch);
    float sp[4];
#pragma unroll
    for (int b = 0; b < 4; ++b) {
      const f16* ep = eap16 + (size_t)ib[b] * 16;
      f16x8 ea = *(const f16x8*)ep;
      f16 ea8 = ep[8];
      f16x4 v = xl4[b] + xr16;                              // v_pk_add_f16
#pragma unroll
      for (int k = 0; k < 8; ++k) v += we16[k] * splat4(ea[k]);  // v_pk_fma_f16
      v += we16[8] * splat4(ea8);
      float s = 0.f;
#pragma unroll
      for (int c = 0; c < 4; ++c) {
        float vf = (float)v[c];
        vf = vf > 0.f ? vf : 0.2f * vf;  // leaky_relu 0.2
        s += att[c] * vf;
      }
      sp[b] = s;
    }
#pragma unroll
    for (int b = 0; b < 4; ++b) {
      sp[b] += __shfl_xor(sp[b], 1);
      sp[b] += __shfl_xor(sp[b], 2);
      sp[b] += __shfl_xor(sp[b], 4);
    }
#pragma unroll
    for (int b = 0; b < 4; ++b) {
      float z = (b < cnt) ? __expf(fminf(sp[b], 75.f)) : 0.f;
      d += z;
#pragma unroll
      for (int c = 0; c < 4; ++c) acc[c] += z * (float)xl4[b][c];
    }
  }
  float inv = 1.f / (d + 1e-16f);  // empty node -> bias only (matches ref)
  float4 cb4 = *(const float4*)(cb_t + ch);
  f16x4 o;
  o[0] = (f16)(acc[0] * inv + cb4.x);
  o[1] = (f16)(acc[1] * inv + cb4.y);
  o[2] = (f16)(acc[2] * inv + cb4.z);
  o[3] = (f16)(acc[3] * inv + cb4.w);
  *(f16x4*)(outb + (size_t)i * 256 + ch) = o;
  // fused BN stats on the f16-rounded output
#pragma unroll
  for (int c = 0; c < 4; ++c) {
    float xv = (float)o[c];
    ls[wave * 512 + ch + c] = xv;
    ls[wave * 512 + 256 + ch + c] = xv * xv;
  }
  __syncthreads();
  float* bp = bns + (blockIdx.x & 7) * 512;  // 8-way partials: contention /8
  for (int q = threadIdx.x; q < 512; q += 256) {
    float sv = ls[q] + ls[512 + q] + ls[1024 + q] + ls[1536 + q];
    atomicAdd(&bp[q], sv);
  }
}

// ------ BatchNorm batch-stats (standalone, head only; writes 8-way partial) ------
__global__ __launch_bounds__(256) void bn_stats_kernel(const f16* __restrict__ v,
                                                       float* __restrict__ sums) {
  __shared__ float ls[512];
  int tid = threadIdx.x;
  for (int i = tid; i < 512; i += 256) ls[i] = 0.f;
  __syncthreads();
  int wave = tid >> 6, lane = tid & 63, ch = lane * 4;
  float s[4] = {0.f, 0.f, 0.f, 0.f}, s2[4] = {0.f, 0.f, 0.f, 0.f};
  for (int r = blockIdx.x * 4 + wave; r < Nn; r += gridDim.x * 4) {
    f16x4 x4 = *(const f16x4*)(v + (size_t)r * 256 + ch);
#pragma unroll
    for (int c = 0; c < 4; ++c) {
      float x = (float)x4[c];
      s[c] += x; s2[c] += x * x;
    }
  }
#pragma unroll
  for (int c = 0; c < 4; ++c) {
    atomicAdd(&ls[ch + c], s[c]);
    atomicAdd(&ls[256 + ch + c], s2[c]);
  }
  __syncthreads();
  float* sp2 = sums + (blockIdx.x & 7) * 512;
  for (int i = tid; i < 512; i += 256) atomicAdd(&sp2[i], ls[i]);
}

// ---------------- final: BN(pbn2)+ReLU folded, 256 -> 3 projection ----------------
__global__ __launch_bounds__(256) void final_kernel(const f16* __restrict__ hq,
                                                    const float* __restrict__ sums,
                                                    const float* __restrict__ gamma,
                                                    const float* __restrict__ beta,
                                                    const float* __restrict__ W,
                                                    const float* __restrict__ b,
                                                    float* __restrict__ out3) {
  int wave = threadIdx.x >> 6, lane = threadIdx.x & 63;
  int n = blockIdx.x * 4 + wave;
  if (n >= Nn) return;
  int ch = lane * 4;
  float su_[4] = {0.f, 0.f, 0.f, 0.f}, sq_[4] = {0.f, 0.f, 0.f, 0.f};
#pragma unroll
  for (int p = 0; p < 8; ++p) {
    float4 su = *(const float4*)(sums + p * 512 + ch);
    float4 sq = *(const float4*)(sums + p * 512 + 256 + ch);
    su_[0] += su.x; su_[1] += su.y; su_[2] += su.z; su_[3] += su.w;
    sq_[0] += sq.x; sq_[1] += sq.y; sq_[2] += sq.z; sq_[3] += sq.w;
  }
  float4 g4 = *(const float4*)(gamma + ch);
  float4 b4 = *(const float4*)(beta + ch);
  float g_[4] = {g4.x, g4.y, g4.z, g4.w};
  float bb_[4] = {b4.x, b4.y, b4.z, b4.w};
  f16x4 h4 = *(const f16x4*)(hq + (size_t)n * 256 + ch);
  float s0 = 0.f, s1 = 0.f, s2 = 0.f;
#pragma unroll
  for (int c = 0; c < 4; ++c) {
    float mu = su_[c] * (1.f / Nn);
    float var = fmaxf(sq_[c] * (1.f / Nn) - mu * mu, 0.f);
    float is = rsqrtf(var + 1e-5f) * g_[c];
    float y = fmaxf(((float)h4[c] - mu) * is + bb_[c], 0.f);
    const float* w = W + (ch + c) * 3;
    s0 += y * w[0]; s1 += y * w[1]; s2 += y * w[2];
  }
  for (int off = 1; off < 64; off <<= 1) {
    s0 += __shfl_xor(s0, off);
    s1 += __shfl_xor(s1, off);
    s2 += __shfl_xor(s2, off);
  }
  if (lane == 0) {
    out3[n * 3 + 0] = s0 + b[0];
    out3[n * 3 + 1] = s1 + b[1];
    out3[n * 3 + 2] = s2 + b[2];
  }
}

extern "C" void kernel_launch(void* const* d_in, const int* in_sizes, int n_in,
                              void* d_out, int out_size, void* d_ws, size_t ws_size,
                              hipStream_t stream) {
  const float* x         = (const float*)d_in[0];
  const float* edge_attr = (const float*)d_in[1];
  const int*   eidx      = (const int*)d_in[2];
  const float* lift_W    = (const float*)d_in[3];
  const float* lift_b    = (const float*)d_in[4];
  const float* Wl        = (const float*)d_in[5];
  const float* bl        = (const float*)d_in[6];
  const float* Wr        = (const float*)d_in[7];
  const float* br        = (const float*)d_in[8];
  const float* We        = (const float*)d_in[9];
  const float* att       = (const float*)d_in[10];
  const float* conv_b    = (const float*)d_in[11];
  const float* bn_g      = (const float*)d_in[12];
  const float* bn_b      = (const float*)d_in[13];
  const float* p1_W      = (const float*)d_in[14];
  const float* p1_b      = (const float*)d_in[15];
  const float* pbn1_g    = (const float*)d_in[16];
  const float* pbn1_b    = (const float*)d_in[17];
  const float* p2_W      = (const float*)d_in[18];
  const float* p2_b      = (const float*)d_in[19];
  const float* pbn2_g    = (const float*)d_in[20];
  const float* pbn2_b    = (const float*)d_in[21];
  const float* p3_W      = (const float*)d_in[22];
  const float* p3_b      = (const float*)d_in[23];
  const int* srcI = eidx;
  const int* dstI = eidx + Ee;

  char* wp = (char*)d_ws;
  auto carve = [&](size_t bytes) -> void* {
    void* p = (void*)wp;
    wp += (bytes + 255) & ~(size_t)255;
    return p;
  };
  // zero region: cstats(32) + bnsA(7 sets x 8 partials x 512) + deg(Nn)
  char*  zr     = (char*)carve((size_t)(32 + 7 * 4096 + Nn) * 4);
  float* cstats = (float*)zr;
  float* bnsA   = (float*)(zr + 32 * 4);
  int*   deg    = (int*)(zr + (32 + 7 * 4096) * 4);
  f16*   eap16  = (f16*)carve((size_t)Ee * 16 * sizeof(f16));
  f16*   h16    = (f16*)carve((size_t)Nn * 256 * sizeof(f16));
  f16*   w16t   = (f16*)carve((size_t)786432 * sizeof(f16));
  float* biascat= (float*)carve((size_t)2560 * sizeof(float));
  f16*   hxlr   = (f16*)carve((size_t)Nn * 512 * sizeof(f16));
  f16*   outb16 = (f16*)carve((size_t)Nn * 256 * sizeof(f16));
  int*   rowptr = (int*)carve((size_t)(Nn + 1) * sizeof(int));
  int*   cursor = (int*)carve((size_t)Nn * sizeof(int));
  int*   perm   = (int*)carve((size_t)Ee * sizeof(int));
  int*   srcp   = (int*)carve((size_t)Ee * sizeof(int));

  hipMemsetAsync(zr, 0, (size_t)(32 + 7 * 4096 + Nn) * 4, stream);

  colstats_kernel<<<64, 256, 0, stream>>>(edge_attr, cstats);
  lift_kernel<<<Nn, 256, 0, stream>>>(x, lift_W, lift_b, h16);
  degree_kernel<<<(Ee + 255) / 256, 256, 0, stream>>>(dstI, deg);
  scan_kernel<<<1, 1024, 0, stream>>>(deg, rowptr, cursor);
  fill_kernel<<<(Ee + 255) / 256, 256, 0, stream>>>(dstI, cursor, perm);
  eaperm_kernel<<<(Ee + 255) / 256, 256, 0, stream>>>(edge_attr, cstats, perm, srcI, srcp, eap16);
  convert_kernel<<<dim3(512, 7), 256, 0, stream>>>(Wl, Wr, p1_W, p2_W, w16t);
  prep_bias_kernel<<<10, 256, 0, stream>>>(bl, br, biascat);

  const int MB = (Nn + 63) / 64;  // 157
  for (int t = 0; t < Tt; ++t) {
    const f16* Ain = (t == 0) ? h16 : outb16;
    const float* sums = (t == 0) ? nullptr : bnsA + (size_t)(t - 1) * 4096;
    int act = (t == 0) ? -1 : 0;
    gemm16_kernel<<<dim3(8, MB), 256, 0, stream>>>(Ain, w16t + (size_t)t * 131072,
                                                   biascat + t * 512, sums,
                                                   bn_g + (t > 0 ? (t - 1) * 256 : 0),
                                                   bn_b + (t > 0 ? (t - 1) * 256 : 0),
                                                   act, hxlr, Nn, 512);
    gat_fused<<<2500, 256, 0, stream>>>(hxlr, eap16, srcp, rowptr,
                                        We + t * 9 * 256, att + t * 256,
                                        conv_b + t * 256, outb16,
                                        bnsA + (size_t)t * 4096);
  }
  // projection head: p1 (BN4+ELU folded), p2 (pbn1+ReLU folded), final (pbn2+ReLU folded)
  f16* pA = hxlr;                    // Nn*256
  f16* pB = hxlr + (size_t)Nn * 256; // Nn*256
  gemm16_kernel<<<dim3(4, MB), 256, 0, stream>>>(outb16, w16t + 655360, p1_b,
                                                 bnsA + 4 * 4096, bn_g + 4 * 256, bn_b + 4 * 256,
                                                 0, pA, Nn, 256);
  bn_stats_kernel<<<128, 256, 0, stream>>>(pA, bnsA + 5 * 4096);
  gemm16_kernel<<<dim3(4, MB), 256, 0, stream>>>(pA, w16t + 720896, p2_b,
                                                 bnsA + 5 * 4096, pbn1_g, pbn1_b,
                                                 1, pB, Nn, 256);
  bn_stats_kernel<<<128, 256, 0, stream>>>(pB, bnsA + 6 * 4096);
  final_kernel<<<2500, 256, 0, stream>>>(pB, bnsA + 6 * 4096, pbn2_g, pbn2_b, p3_W, p3_b,
                                         (float*)d_out);
}

// Round 16
// 585.573 us; speedup vs baseline: 1.0811x; 1.0411x over previous
//
#include <hip/hip_runtime.h>

#define Nn 10000
#define Ee 160000
#define HID 256
#define EDIM 9
#define INDIM 10
#define Tt 5

typedef _Float16 f16;
typedef _Float16 f16x8 __attribute__((ext_vector_type(8)));
typedef _Float16 f16x4 __attribute__((ext_vector_type(4)));
typedef float f32x4 __attribute__((ext_vector_type(4)));

// ------ prologue A: edge-attr column stats (blocks 0-63) + degree histogram ------
// Disjoint block ranges; bodies identical to the old separate kernels.
__global__ __launch_bounds__(256) void prep_kernel(const float* __restrict__ in,
                                                   const int* __restrict__ dst,
                                                   float* __restrict__ cs,
                                                   int* __restrict__ deg) {
  if (blockIdx.x < 64) {
    float s[9], s2[9];
#pragma unroll
    for (int k = 0; k < 9; ++k) { s[k] = 0.f; s2[k] = 0.f; }
    for (int i = blockIdx.x * 256 + threadIdx.x; i < Ee; i += 64 * 256) {
#pragma unroll
      for (int k = 0; k < 9; ++k) {
        float v = in[i * 9 + k];
        s[k] += v; s2[k] += v * v;
      }
    }
#pragma unroll
    for (int k = 0; k < 9; ++k) {
      for (int off = 1; off < 64; off <<= 1) {
        s[k] += __shfl_xor(s[k], off);
        s2[k] += __shfl_xor(s2[k], off);
      }
    }
    if ((threadIdx.x & 63) == 0) {
#pragma unroll
      for (int k = 0; k < 9; ++k) {
        atomicAdd(&cs[k], s[k]);
        atomicAdd(&cs[16 + k], s2[k]);
      }
    }
  } else {
    int e = (blockIdx.x - 64) * 256 + threadIdx.x;
    if (e < Ee) atomicAdd(&deg[dst[e]], 1);
  }
}

// ---------------- lift: h = relu(x @ lift_W + b), stored fp16 ----------------
__global__ __launch_bounds__(256) void lift_kernel(const float* __restrict__ x,
                                                   const float* __restrict__ W,
                                                   const float* __restrict__ b,
                                                   f16* __restrict__ hq) {
  __shared__ float xs[INDIM];
  int n = blockIdx.x, ch = threadIdx.x;
  if (ch < INDIM) xs[ch] = x[n * INDIM + ch];
  __syncthreads();
  float s = b[ch];
#pragma unroll
  for (int k = 0; k < INDIM; ++k) s += xs[k] * W[k * 256 + ch];
  hq[n * 256 + ch] = (f16)fmaxf(s, 0.f);
}

// ---------------- CSR rowptr scan (single block) ----------------
__global__ __launch_bounds__(1024) void scan_kernel(const int* __restrict__ deg,
                                                    int* __restrict__ rowptr,
                                                    int* __restrict__ cursor) {
  __shared__ int part[1024];
  int tid = threadIdx.x;
  const int CH = (Nn + 1023) / 1024;
  int start = tid * CH;
  int s = 0;
  for (int i = 0; i < CH; ++i) { int idx = start + i; if (idx < Nn) s += deg[idx]; }
  part[tid] = s;
  __syncthreads();
  for (int off = 1; off < 1024; off <<= 1) {
    int v = part[tid];
    int w = (tid >= off) ? part[tid - off] : 0;
    __syncthreads();
    part[tid] = v + w;
    __syncthreads();
  }
  int run = part[tid] - s;  // exclusive prefix
  for (int i = 0; i < CH; ++i) {
    int idx = start + i;
    if (idx < Nn) { rowptr[idx] = run; cursor[idx] = run; run += deg[idx]; }
  }
  if (tid == 0) rowptr[Nn] = Ee;
}

// ---- fused CSR fill + src permute + edge-attr normalize (f32, stride 12) ----
__global__ __launch_bounds__(256) void fill_eaperm_kernel(const float* __restrict__ edge_attr,
                                                          const float* __restrict__ cs,
                                                          const int* __restrict__ srcIn,
                                                          const int* __restrict__ dstIn,
                                                          int* __restrict__ cursor,
                                                          int* __restrict__ srcp,
                                                          float* __restrict__ eap) {
  int e = blockIdx.x * 256 + threadIdx.x;
  if (e >= Ee) return;
  int pos = atomicAdd(&cursor[dstIn[e]], 1);
  srcp[pos] = srcIn[e];
  const float* a = edge_attr + e * 9;
  float o[12];
#pragma unroll
  for (int k = 0; k < 9; ++k) {
    float mu = cs[k] * (1.f / Ee);
    float var = fmaxf(cs[16 + k] * (1.f / Ee) - mu * mu, 0.f);
    o[k] = (a[k] - mu) / (sqrtf(var) + 1e-8f);
  }
  o[9] = o[10] = o[11] = 0.f;
  float4 v0 = {o[0], o[1], o[2], o[3]};
  float4 v1 = {o[4], o[5], o[6], o[7]};
  float4 v2 = {o[8], o[9], o[10], o[11]};
  *(float4*)(eap + (size_t)pos * 12 + 0) = v0;
  *(float4*)(eap + (size_t)pos * 12 + 4) = v1;
  *(float4*)(eap + (size_t)pos * 12 + 8) = v2;
}

// ------ weight convert fp32->fp16 transposed (+ bias concat on slice y=7) ------
__global__ __launch_bounds__(256) void convert_kernel(const float* __restrict__ Wl,
                                                      const float* __restrict__ Wr,
                                                      const float* __restrict__ p1,
                                                      const float* __restrict__ p2,
                                                      const float* __restrict__ bl,
                                                      const float* __restrict__ br,
                                                      f16* __restrict__ wt,
                                                      float* __restrict__ biascat) {
  int nrow = blockIdx.x, s = blockIdx.y, k = threadIdx.x;
  if (s == 7) {
    int flat = nrow * 256 + k;
    if (flat < 2560) {
      int t = flat >> 9, c = flat & 511;
      biascat[flat] = (c < 256) ? bl[t * 256 + c] : br[t * 256 + c - 256];
    }
    return;
  }
  const float* srcp; int n = nrow; size_t dst;
  if (s < 5) {
    dst = (size_t)s * 131072 + (size_t)nrow * 256 + k;
    if (nrow < 256) srcp = Wl + s * 65536;
    else { srcp = Wr + s * 65536; n = nrow - 256; }
  } else {
    if (nrow >= 256) return;
    dst = 655360 + (size_t)(s - 5) * 65536 + (size_t)nrow * 256 + k;
    srcp = (s == 5) ? p1 : p2;
  }
  wt[dst] = (f16)srcp[k * 256 + n];
}

// ------------- fp16 MFMA GEMM: A staged in LDS, B streamed from L2 -------------
__global__ __launch_bounds__(256) void gemm16_kernel(const f16* __restrict__ A,
                                                     const f16* __restrict__ BT,
                                                     const float* __restrict__ bias,
                                                     const float* __restrict__ sums,
                                                     const float* __restrict__ gamma,
                                                     const float* __restrict__ beta,
                                                     int act,
                                                     f16* __restrict__ out,
                                                     int M, int OS) {
  __shared__ __align__(16) f16 As[64][264];
  const int tid = threadIdx.x;
  const int wave = tid >> 6, lane = tid & 63;
  const int l15 = lane & 15, quad = lane >> 4;
  const int m0 = blockIdx.y * 64, n0 = blockIdx.x * 64;
  const int wm = (wave >> 1) * 32, wn = (wave & 1) * 32;
  const int colbase = (tid & 31) * 8, rowbase = tid >> 5;
  float sA[8], tA[8];
  if (act >= 0) {
#pragma unroll
    for (int c4 = 0; c4 < 2; ++c4) {
      float su_[4] = {0.f, 0.f, 0.f, 0.f}, sq_[4] = {0.f, 0.f, 0.f, 0.f};
#pragma unroll
      for (int p = 0; p < 8; ++p) {
        float4 su = *(const float4*)(sums + p * 512 + colbase + c4 * 4);
        float4 sq = *(const float4*)(sums + p * 512 + 256 + colbase + c4 * 4);
        su_[0] += su.x; su_[1] += su.y; su_[2] += su.z; su_[3] += su.w;
        sq_[0] += sq.x; sq_[1] += sq.y; sq_[2] += sq.z; sq_[3] += sq.w;
      }
      float4 g4 = *(const float4*)(gamma + colbase + c4 * 4);
      float4 b4 = *(const float4*)(beta + colbase + c4 * 4);
      float g_[4] = {g4.x, g4.y, g4.z, g4.w};
      float b_[4] = {b4.x, b4.y, b4.z, b4.w};
#pragma unroll
      for (int c = 0; c < 4; ++c) {
        float mu = su_[c] * (1.f / Nn);
        float var = fmaxf(sq_[c] * (1.f / Nn) - mu * mu, 0.f);
        float is = rsqrtf(var + 1e-5f) * g_[c];
        sA[c4 * 4 + c] = is;
        tA[c4 * 4 + c] = b_[c] - mu * is;
      }
    }
  }
  // stage A panel (64x256) only: 8 x 16B chunks per thread
#pragma unroll
  for (int i = 0; i < 8; ++i) {
    int c = tid + 256 * i;
    int row = c >> 5, col = (c & 31) * 8;
    f16x8 av = {};
    int gm = m0 + row;
    if (gm < M) av = *(const f16x8*)(A + (size_t)gm * 256 + col);
    if (act >= 0) {
#pragma unroll
      for (int e = 0; e < 8; ++e) {
        float y = (float)av[e] * sA[e] + tA[e];
        if (act == 0) y = y > 0.f ? y : (__expf(y) - 1.f);
        else y = fmaxf(y, 0.f);
        av[e] = (f16)y;
      }
    }
    *(f16x8*)(&As[row][col]) = av;
  }
  __syncthreads();
  const f16* pb0 = BT + (size_t)(n0 + wn + l15) * 256 + quad * 8;
  const f16* pb1 = BT + (size_t)(n0 + wn + 16 + l15) * 256 + quad * 8;
  f32x4 zero4 = {0.f, 0.f, 0.f, 0.f};
  f32x4 acc[2][2] = {{zero4, zero4}, {zero4, zero4}};
#pragma unroll
  for (int kk = 0; kk < 256; kk += 32) {
    f16x8 a0 = *(const f16x8*)(&As[wm + l15][kk + quad * 8]);
    f16x8 a1 = *(const f16x8*)(&As[wm + 16 + l15][kk + quad * 8]);
    f16x8 b0 = *(const f16x8*)(pb0 + kk);
    f16x8 b1 = *(const f16x8*)(pb1 + kk);
    acc[0][0] = __builtin_amdgcn_mfma_f32_16x16x32_f16(a0, b0, acc[0][0], 0, 0, 0);
    acc[0][1] = __builtin_amdgcn_mfma_f32_16x16x32_f16(a0, b1, acc[0][1], 0, 0, 0);
    acc[1][0] = __builtin_amdgcn_mfma_f32_16x16x32_f16(a1, b0, acc[1][0], 0, 0, 0);
    acc[1][1] = __builtin_amdgcn_mfma_f32_16x16x32_f16(a1, b1, acc[1][1], 0, 0, 0);
  }
  // epilogue: bias add, fp16 via LDS transpose for coalesced 16B stores
  __syncthreads();
  f16* Cs = (f16*)&As[0][0];  // 64 x 72 tile (reuses As)
#pragma unroll
  for (int ni = 0; ni < 2; ++ni) {
    int nl = wn + ni * 16 + l15;
    float bv = bias[n0 + nl];
#pragma unroll
    for (int mi = 0; mi < 2; ++mi)
#pragma unroll
      for (int r = 0; r < 4; ++r)
        Cs[(wm + mi * 16 + quad * 4 + r) * 72 + nl] = (f16)(acc[mi][ni][r] + bv);
  }
  __syncthreads();
  {
    int row = tid >> 2, c4 = (tid & 3) * 16;
    int gm = m0 + row;
    if (gm < M) {
      f16x8 v0 = *(const f16x8*)(&Cs[row * 72 + c4]);
      f16x8 v1 = *(const f16x8*)(&Cs[row * 72 + c4 + 8]);
      *(f16x8*)(out + (size_t)gm * OS + n0 + c4) = v0;
      *(f16x8*)(out + (size_t)gm * OS + n0 + c4 + 8) = v1;
    }
  }
}

// ---- Fused GATv2 + BN stats: wave/node, batch-4 edges (R13 best variant) ----
__global__ __launch_bounds__(256) void gat_fused(const f16* __restrict__ hxlr,
                                                 const float* __restrict__ eap,
                                                 const int* __restrict__ srcp,
                                                 const int* __restrict__ rowptr,
                                                 const float* __restrict__ We_t,
                                                 const float* __restrict__ att_t,
                                                 const float* __restrict__ cb_t,
                                                 f16* __restrict__ outb,
                                                 float* __restrict__ bns) {
  __shared__ float ls[2048];  // [wave][sum 256 | sumsq 256]
  int wave = threadIdx.x >> 6, lane = threadIdx.x & 63;
  int i = blockIdx.x * 4 + wave;  // 2500 * 4 == Nn exactly
  int ch = lane * 4;  // lane owns flat channels [ch, ch+4); head = lane>>3
  float we[9][4];
#pragma unroll
  for (int k = 0; k < 9; ++k) {
    float4 w4 = *(const float4*)(We_t + k * 256 + ch);
    we[k][0] = w4.x; we[k][1] = w4.y; we[k][2] = w4.z; we[k][3] = w4.w;
  }
  float4 a4 = *(const float4*)(att_t + ch);
  float att[4] = {a4.x, a4.y, a4.z, a4.w};
  f16x4 xr4 = *(const f16x4*)(hxlr + (size_t)i * 512 + 256 + ch);
  float xri[4] = {(float)xr4[0], (float)xr4[1], (float)xr4[2], (float)xr4[3]};
  float acc[4] = {0.f, 0.f, 0.f, 0.f};
  float d = 0.f;
  int r0 = rowptr[i], r1 = rowptr[i + 1];
  for (int base = r0; base < r1; base += 4) {
    int cnt = r1 - base;  // >= 1
    int ib[4];
#pragma unroll
    for (int b = 0; b < 4; ++b) ib[b] = base + (b < cnt ? b : cnt - 1);
    int js[4];
#pragma unroll
    for (int b = 0; b < 4; ++b) js[b] = srcp[ib[b]];
    float xlv[4][4];
#pragma unroll
    for (int b = 0; b < 4; ++b) {
      f16x4 v4 = *(const f16x4*)(hxlr + (size_t)js[b] * 512 + ch);
      xlv[b][0] = (float)v4[0]; xlv[b][1] = (float)v4[1];
      xlv[b][2] = (float)v4[2]; xlv[b][3] = (float)v4[3];
    }
    float sp[4];
#pragma unroll
    for (int b = 0; b < 4; ++b) {
      const float* ep = eap + (size_t)ib[b] * 12;
      float4 e0 = *(const float4*)ep;
      float4 e1 = *(const float4*)(ep + 4);
      float e8 = ep[8];
      float s = 0.f;
#pragma unroll
      for (int c = 0; c < 4; ++c) {
        float v = xlv[b][c] + xri[c];
        v += e0.x * we[0][c] + e0.y * we[1][c] + e0.z * we[2][c] + e0.w * we[3][c];
        v += e1.x * we[4][c] + e1.y * we[5][c] + e1.z * we[6][c] + e1.w * we[7][c];
        v += e8 * we[8][c];
        v = v > 0.f ? v : 0.2f * v;  // leaky_relu 0.2
        s += att[c] * v;
      }
      sp[b] = s;
    }
#pragma unroll
    for (int b = 0; b < 4; ++b) {
      sp[b] += __shfl_xor(sp[b], 1);
      sp[b] += __shfl_xor(sp[b], 2);
      sp[b] += __shfl_xor(sp[b], 4);
    }
#pragma unroll
    for (int b = 0; b < 4; ++b) {
      float z = (b < cnt) ? __expf(fminf(sp[b], 75.f)) : 0.f;
      d += z;
#pragma unroll
      for (int c = 0; c < 4; ++c) acc[c] += z * xlv[b][c];
    }
  }
  float inv = 1.f / (d + 1e-16f);  // empty node -> bias only (matches ref)
  float4 cb4 = *(const float4*)(cb_t + ch);
  f16x4 o;
  o[0] = (f16)(acc[0] * inv + cb4.x);
  o[1] = (f16)(acc[1] * inv + cb4.y);
  o[2] = (f16)(acc[2] * inv + cb4.z);
  o[3] = (f16)(acc[3] * inv + cb4.w);
  *(f16x4*)(outb + (size_t)i * 256 + ch) = o;
  // fused BN stats on the f16-rounded output (identical values to old bn_stats)
#pragma unroll
  for (int c = 0; c < 4; ++c) {
    float xv = (float)o[c];
    ls[wave * 512 + ch + c] = xv;
    ls[wave * 512 + 256 + ch + c] = xv * xv;
  }
  __syncthreads();
  float* bp = bns + (blockIdx.x & 7) * 512;  // 8-way partials: contention /8
  for (int q = threadIdx.x; q < 512; q += 256) {
    float sv = ls[q] + ls[512 + q] + ls[1024 + q] + ls[1536 + q];
    atomicAdd(&bp[q], sv);
  }
}

// ------ BatchNorm batch-stats (standalone, head only; writes 8-way partial) ------
__global__ __launch_bounds__(256) void bn_stats_kernel(const f16* __restrict__ v,
                                                       float* __restrict__ sums) {
  __shared__ float ls[512];
  int tid = threadIdx.x;
  for (int i = tid; i < 512; i += 256) ls[i] = 0.f;
  __syncthreads();
  int wave = tid >> 6, lane = tid & 63, ch = lane * 4;
  float s[4] = {0.f, 0.f, 0.f, 0.f}, s2[4] = {0.f, 0.f, 0.f, 0.f};
  for (int r = blockIdx.x * 4 + wave; r < Nn; r += gridDim.x * 4) {
    f16x4 x4 = *(const f16x4*)(v + (size_t)r * 256 + ch);
#pragma unroll
    for (int c = 0; c < 4; ++c) {
      float x = (float)x4[c];
      s[c] += x; s2[c] += x * x;
    }
  }
#pragma unroll
  for (int c = 0; c < 4; ++c) {
    atomicAdd(&ls[ch + c], s[c]);
    atomicAdd(&ls[256 + ch + c], s2[c]);
  }
  __syncthreads();
  float* sp2 = sums + (blockIdx.x & 7) * 512;
  for (int i = tid; i < 512; i += 256) atomicAdd(&sp2[i], ls[i]);
}

// ---------------- final: BN(pbn2)+ReLU folded, 256 -> 3 projection ----------------
__global__ __launch_bounds__(256) void final_kernel(const f16* __restrict__ hq,
                                                    const float* __restrict__ sums,
                                                    const float* __restrict__ gamma,
                                                    const float* __restrict__ beta,
                                                    const float* __restrict__ W,
                                                    const float* __restrict__ b,
                                                    float* __restrict__ out3) {
  int wave = threadIdx.x >> 6, lane = threadIdx.x & 63;
  int n = blockIdx.x * 4 + wave;
  if (n >= Nn) return;
  int ch = lane * 4;
  float su_[4] = {0.f, 0.f, 0.f, 0.f}, sq_[4] = {0.f, 0.f, 0.f, 0.f};
#pragma unroll
  for (int p = 0; p < 8; ++p) {
    float4 su = *(const float4*)(sums + p * 512 + ch);
    float4 sq = *(const float4*)(sums + p * 512 + 256 + ch);
    su_[0] += su.x; su_[1] += su.y; su_[2] += su.z; su_[3] += su.w;
    sq_[0] += sq.x; sq_[1] += sq.y; sq_[2] += sq.z; sq_[3] += sq.w;
  }
  float4 g4 = *(const float4*)(gamma + ch);
  float4 b4 = *(const float4*)(beta + ch);
  float g_[4] = {g4.x, g4.y, g4.z, g4.w};
  float bb_[4] = {b4.x, b4.y, b4.z, b4.w};
  f16x4 h4 = *(const f16x4*)(hq + (size_t)n * 256 + ch);
  float s0 = 0.f, s1 = 0.f, s2 = 0.f;
#pragma unroll
  for (int c = 0; c < 4; ++c) {
    float mu = su_[c] * (1.f / Nn);
    float var = fmaxf(sq_[c] * (1.f / Nn) - mu * mu, 0.f);
    float is = rsqrtf(var + 1e-5f) * g_[c];
    float y = fmaxf(((float)h4[c] - mu) * is + bb_[c], 0.f);
    const float* w = W + (ch + c) * 3;
    s0 += y * w[0]; s1 += y * w[1]; s2 += y * w[2];
  }
  for (int off = 1; off < 64; off <<= 1) {
    s0 += __shfl_xor(s0, off);
    s1 += __shfl_xor(s1, off);
    s2 += __shfl_xor(s2, off);
  }
  if (lane == 0) {
    out3[n * 3 + 0] = s0 + b[0];
    out3[n * 3 + 1] = s1 + b[1];
    out3[n * 3 + 2] = s2 + b[2];
  }
}

extern "C" void kernel_launch(void* const* d_in, const int* in_sizes, int n_in,
                              void* d_out, int out_size, void* d_ws, size_t ws_size,
                              hipStream_t stream) {
  const float* x         = (const float*)d_in[0];
  const float* edge_attr = (const float*)d_in[1];
  const int*   eidx      = (const int*)d_in[2];
  const float* lift_W    = (const float*)d_in[3];
  const float* lift_b    = (const float*)d_in[4];
  const float* Wl        = (const float*)d_in[5];
  const float* bl        = (const float*)d_in[6];
  const float* Wr        = (const float*)d_in[7];
  const float* br        = (const float*)d_in[8];
  const float* We        = (const float*)d_in[9];
  const float* att       = (const float*)d_in[10];
  const float* conv_b    = (const float*)d_in[11];
  const float* bn_g      = (const float*)d_in[12];
  const float* bn_b      = (const float*)d_in[13];
  const float* p1_W      = (const float*)d_in[14];
  const float* p1_b      = (const float*)d_in[15];
  const float* pbn1_g    = (const float*)d_in[16];
  const float* pbn1_b    = (const float*)d_in[17];
  const float* p2_W      = (const float*)d_in[18];
  const float* p2_b      = (const float*)d_in[19];
  const float* pbn2_g    = (const float*)d_in[20];
  const float* pbn2_b    = (const float*)d_in[21];
  const float* p3_W      = (const float*)d_in[22];
  const float* p3_b      = (const float*)d_in[23];
  const int* srcI = eidx;
  const int* dstI = eidx + Ee;

  char* wp = (char*)d_ws;
  auto carve = [&](size_t bytes) -> void* {
    void* p = (void*)wp;
    wp += (bytes + 255) & ~(size_t)255;
    return p;
  };
  // zero region: cstats(32) + bnsA(7 sets x 8 partials x 512) + deg(Nn)
  char*  zr     = (char*)carve((size_t)(32 + 7 * 4096 + Nn) * 4);
  float* cstats = (float*)zr;
  float* bnsA   = (float*)(zr + 32 * 4);
  int*   deg    = (int*)(zr + (32 + 7 * 4096) * 4);
  float* eap    = (float*)carve((size_t)Ee * 12 * sizeof(float));
  f16*   h16    = (f16*)carve((size_t)Nn * 256 * sizeof(f16));
  f16*   w16t   = (f16*)carve((size_t)786432 * sizeof(f16));
  float* biascat= (float*)carve((size_t)2560 * sizeof(float));
  f16*   hxlr   = (f16*)carve((size_t)Nn * 512 * sizeof(f16));
  f16*   outb16 = (f16*)carve((size_t)Nn * 256 * sizeof(f16));
  int*   rowptr = (int*)carve((size_t)(Nn + 1) * sizeof(int));
  int*   cursor = (int*)carve((size_t)Nn * sizeof(int));
  int*   srcp   = (int*)carve((size_t)Ee * sizeof(int));

  hipMemsetAsync(zr, 0, (size_t)(32 + 7 * 4096 + Nn) * 4, stream);

  prep_kernel<<<64 + (Ee + 255) / 256, 256, 0, stream>>>(edge_attr, dstI, cstats, deg);
  lift_kernel<<<Nn, 256, 0, stream>>>(x, lift_W, lift_b, h16);
  scan_kernel<<<1, 1024, 0, stream>>>(deg, rowptr, cursor);
  fill_eaperm_kernel<<<(Ee + 255) / 256, 256, 0, stream>>>(edge_attr, cstats, srcI, dstI,
                                                           cursor, srcp, eap);
  convert_kernel<<<dim3(512, 8), 256, 0, stream>>>(Wl, Wr, p1_W, p2_W, bl, br, w16t, biascat);

  const int MB = (Nn + 63) / 64;  // 157
  for (int t = 0; t < Tt; ++t) {
    const f16* Ain = (t == 0) ? h16 : outb16;
    const float* sums = (t == 0) ? nullptr : bnsA + (size_t)(t - 1) * 4096;
    int act = (t == 0) ? -1 : 0;
    gemm16_kernel<<<dim3(8, MB), 256, 0, stream>>>(Ain, w16t + (size_t)t * 131072,
                                                   biascat + t * 512, sums,
                                                   bn_g + (t > 0 ? (t - 1) * 256 : 0),
                                                   bn_b + (t > 0 ? (t - 1) * 256 : 0),
                                                   act, hxlr, Nn, 512);
    gat_fused<<<2500, 256, 0, stream>>>(hxlr, eap, srcp, rowptr,
                                        We + t * 9 * 256, att + t * 256,
                                        conv_b + t * 256, outb16,
                                        bnsA + (size_t)t * 4096);
  }
  // projection head: p1 (BN4+ELU folded), p2 (pbn1+ReLU folded), final (pbn2+ReLU folded)
  f16* pA = hxlr;                    // Nn*256
  f16* pB = hxlr + (size_t)Nn * 256; // Nn*256
  gemm16_kernel<<<dim3(4, MB), 256, 0, stream>>>(outb16, w16t + 655360, p1_b,
                                                 bnsA + 4 * 4096, bn_g + 4 * 256, bn_b + 4 * 256,
                                                 0, pA, Nn, 256);
  bn_stats_kernel<<<128, 256, 0, stream>>>(pA, bnsA + 5 * 4096);
  gemm16_kernel<<<dim3(4, MB), 256, 0, stream>>>(pA, w16t + 720896, p2_b,
                                                 bnsA + 5 * 4096, pbn1_g, pbn1_b,
                                                 1, pB, Nn, 256);
  bn_stats_kernel<<<128, 256, 0, stream>>>(pB, bnsA + 6 * 4096);
  final_kernel<<<2500, 256, 0, stream>>>(pB, bnsA + 6 * 4096, pbn2_g, pbn2_b, p3_W, p3_b,
                                         (float*)d_out);
}

// Round 17
// 569.784 us; speedup vs baseline: 1.1111x; 1.0277x over previous
//
#include <hip/hip_runtime.h>

#define Nn 10000
#define Ee 160000
#define HID 256
#define EDIM 9
#define INDIM 10
#define Tt 5

typedef _Float16 f16;
typedef _Float16 f16x8 __attribute__((ext_vector_type(8)));
typedef _Float16 f16x4 __attribute__((ext_vector_type(4)));
typedef float f32x4 __attribute__((ext_vector_type(4)));

// ------ prologue A: edge-attr column stats (blocks 0-63) + degree histogram ------
__global__ __launch_bounds__(256) void prep_kernel(const float* __restrict__ in,
                                                   const int* __restrict__ dst,
                                                   float* __restrict__ cs,
                                                   int* __restrict__ deg) {
  if (blockIdx.x < 64) {
    float s[9], s2[9];
#pragma unroll
    for (int k = 0; k < 9; ++k) { s[k] = 0.f; s2[k] = 0.f; }
    for (int i = blockIdx.x * 256 + threadIdx.x; i < Ee; i += 64 * 256) {
#pragma unroll
      for (int k = 0; k < 9; ++k) {
        float v = in[i * 9 + k];
        s[k] += v; s2[k] += v * v;
      }
    }
#pragma unroll
    for (int k = 0; k < 9; ++k) {
      for (int off = 1; off < 64; off <<= 1) {
        s[k] += __shfl_xor(s[k], off);
        s2[k] += __shfl_xor(s2[k], off);
      }
    }
    if ((threadIdx.x & 63) == 0) {
#pragma unroll
      for (int k = 0; k < 9; ++k) {
        atomicAdd(&cs[k], s[k]);
        atomicAdd(&cs[16 + k], s2[k]);
      }
    }
  } else {
    int e = (blockIdx.x - 64) * 256 + threadIdx.x;
    if (e < Ee) atomicAdd(&deg[dst[e]], 1);
  }
}

// ---------------- lift: h = relu(x @ lift_W + b), stored fp16 ----------------
__global__ __launch_bounds__(256) void lift_kernel(const float* __restrict__ x,
                                                   const float* __restrict__ W,
                                                   const float* __restrict__ b,
                                                   f16* __restrict__ hq) {
  __shared__ float xs[INDIM];
  int n = blockIdx.x, ch = threadIdx.x;
  if (ch < INDIM) xs[ch] = x[n * INDIM + ch];
  __syncthreads();
  float s = b[ch];
#pragma unroll
  for (int k = 0; k < INDIM; ++k) s += xs[k] * W[k * 256 + ch];
  hq[n * 256 + ch] = (f16)fmaxf(s, 0.f);
}

// ---------------- CSR rowptr scan (single block) ----------------
__global__ __launch_bounds__(1024) void scan_kernel(const int* __restrict__ deg,
                                                    int* __restrict__ rowptr,
                                                    int* __restrict__ cursor) {
  __shared__ int part[1024];
  int tid = threadIdx.x;
  const int CH = (Nn + 1023) / 1024;
  int start = tid * CH;
  int s = 0;
  for (int i = 0; i < CH; ++i) { int idx = start + i; if (idx < Nn) s += deg[idx]; }
  part[tid] = s;
  __syncthreads();
  for (int off = 1; off < 1024; off <<= 1) {
    int v = part[tid];
    int w = (tid >= off) ? part[tid - off] : 0;
    __syncthreads();
    part[tid] = v + w;
    __syncthreads();
  }
  int run = part[tid] - s;  // exclusive prefix
  for (int i = 0; i < CH; ++i) {
    int idx = start + i;
    if (idx < Nn) { rowptr[idx] = run; cursor[idx] = run; run += deg[idx]; }
  }
  if (tid == 0) rowptr[Nn] = Ee;
}

// ---- fused CSR fill + src permute + edge-attr normalize (f32, stride 12) ----
__global__ __launch_bounds__(256) void fill_eaperm_kernel(const float* __restrict__ edge_attr,
                                                          const float* __restrict__ cs,
                                                          const int* __restrict__ srcIn,
                                                          const int* __restrict__ dstIn,
                                                          int* __restrict__ cursor,
                                                          int* __restrict__ srcp,
                                                          float* __restrict__ eap) {
  int e = blockIdx.x * 256 + threadIdx.x;
  if (e >= Ee) return;
  int pos = atomicAdd(&cursor[dstIn[e]], 1);
  srcp[pos] = srcIn[e];
  const float* a = edge_attr + e * 9;
  float o[12];
#pragma unroll
  for (int k = 0; k < 9; ++k) {
    float mu = cs[k] * (1.f / Ee);
    float var = fmaxf(cs[16 + k] * (1.f / Ee) - mu * mu, 0.f);
    o[k] = (a[k] - mu) / (sqrtf(var) + 1e-8f);
  }
  o[9] = o[10] = o[11] = 0.f;
  float4 v0 = {o[0], o[1], o[2], o[3]};
  float4 v1 = {o[4], o[5], o[6], o[7]};
  float4 v2 = {o[8], o[9], o[10], o[11]};
  *(float4*)(eap + (size_t)pos * 12 + 0) = v0;
  *(float4*)(eap + (size_t)pos * 12 + 4) = v1;
  *(float4*)(eap + (size_t)pos * 12 + 8) = v2;
}

// ------ weight convert fp32->fp16 transposed (+ bias concat on slice y=7) ------
__global__ __launch_bounds__(256) void convert_kernel(const float* __restrict__ Wl,
                                                      const float* __restrict__ Wr,
                                                      const float* __restrict__ p1,
                                                      const float* __restrict__ p2,
                                                      const float* __restrict__ bl,
                                                      const float* __restrict__ br,
                                                      f16* __restrict__ wt,
                                                      float* __restrict__ biascat) {
  int nrow = blockIdx.x, s = blockIdx.y, k = threadIdx.x;
  if (s == 7) {
    int flat = nrow * 256 + k;
    if (flat < 2560) {
      int t = flat >> 9, c = flat & 511;
      biascat[flat] = (c < 256) ? bl[t * 256 + c] : br[t * 256 + c - 256];
    }
    return;
  }
  const float* srcp; int n = nrow; size_t dst;
  if (s < 5) {
    dst = (size_t)s * 131072 + (size_t)nrow * 256 + k;
    if (nrow < 256) srcp = Wl + s * 65536;
    else { srcp = Wr + s * 65536; n = nrow - 256; }
  } else {
    if (nrow >= 256) return;
    dst = 655360 + (size_t)(s - 5) * 65536 + (size_t)nrow * 256 + k;
    srcp = (s == 5) ? p1 : p2;
  }
  wt[dst] = (f16)srcp[k * 256 + n];
}

// ------------- fp16 MFMA GEMM: A staged in LDS, B streamed from L2 -------------
// statsout != nullptr: fused BN stats of the f16-rounded output via register
// reduction (shfl over quad lanes) into 8-way partial buffers. No LDS scans.
__global__ __launch_bounds__(256) void gemm16_kernel(const f16* __restrict__ A,
                                                     const f16* __restrict__ BT,
                                                     const float* __restrict__ bias,
                                                     const float* __restrict__ sums,
                                                     const float* __restrict__ gamma,
                                                     const float* __restrict__ beta,
                                                     int act,
                                                     f16* __restrict__ out,
                                                     int M, int OS,
                                                     float* __restrict__ statsout) {
  __shared__ __align__(16) f16 As[64][264];
  const int tid = threadIdx.x;
  const int wave = tid >> 6, lane = tid & 63;
  const int l15 = lane & 15, quad = lane >> 4;
  const int m0 = blockIdx.y * 64, n0 = blockIdx.x * 64;
  const int wm = (wave >> 1) * 32, wn = (wave & 1) * 32;
  const int colbase = (tid & 31) * 8, rowbase = tid >> 5;
  float sA[8], tA[8];
  if (act >= 0) {
#pragma unroll
    for (int c4 = 0; c4 < 2; ++c4) {
      float su_[4] = {0.f, 0.f, 0.f, 0.f}, sq_[4] = {0.f, 0.f, 0.f, 0.f};
#pragma unroll
      for (int p = 0; p < 8; ++p) {
        float4 su = *(const float4*)(sums + p * 512 + colbase + c4 * 4);
        float4 sq = *(const float4*)(sums + p * 512 + 256 + colbase + c4 * 4);
        su_[0] += su.x; su_[1] += su.y; su_[2] += su.z; su_[3] += su.w;
        sq_[0] += sq.x; sq_[1] += sq.y; sq_[2] += sq.z; sq_[3] += sq.w;
      }
      float4 g4 = *(const float4*)(gamma + colbase + c4 * 4);
      float4 b4 = *(const float4*)(beta + colbase + c4 * 4);
      float g_[4] = {g4.x, g4.y, g4.z, g4.w};
      float b_[4] = {b4.x, b4.y, b4.z, b4.w};
#pragma unroll
      for (int c = 0; c < 4; ++c) {
        float mu = su_[c] * (1.f / Nn);
        float var = fmaxf(sq_[c] * (1.f / Nn) - mu * mu, 0.f);
        float is = rsqrtf(var + 1e-5f) * g_[c];
        sA[c4 * 4 + c] = is;
        tA[c4 * 4 + c] = b_[c] - mu * is;
      }
    }
  }
  // stage A panel (64x256) only: 8 x 16B chunks per thread
#pragma unroll
  for (int i = 0; i < 8; ++i) {
    int c = tid + 256 * i;
    int row = c >> 5, col = (c & 31) * 8;
    f16x8 av = {};
    int gm = m0 + row;
    if (gm < M) av = *(const f16x8*)(A + (size_t)gm * 256 + col);
    if (act >= 0) {
#pragma unroll
      for (int e = 0; e < 8; ++e) {
        float y = (float)av[e] * sA[e] + tA[e];
        if (act == 0) y = y > 0.f ? y : (__expf(y) - 1.f);
        else y = fmaxf(y, 0.f);
        av[e] = (f16)y;
      }
    }
    *(f16x8*)(&As[row][col]) = av;
  }
  __syncthreads();
  const f16* pb0 = BT + (size_t)(n0 + wn + l15) * 256 + quad * 8;
  const f16* pb1 = BT + (size_t)(n0 + wn + 16 + l15) * 256 + quad * 8;
  f32x4 zero4 = {0.f, 0.f, 0.f, 0.f};
  f32x4 acc[2][2] = {{zero4, zero4}, {zero4, zero4}};
#pragma unroll
  for (int kk = 0; kk < 256; kk += 32) {
    f16x8 a0 = *(const f16x8*)(&As[wm + l15][kk + quad * 8]);
    f16x8 a1 = *(const f16x8*)(&As[wm + 16 + l15][kk + quad * 8]);
    f16x8 b0 = *(const f16x8*)(pb0 + kk);
    f16x8 b1 = *(const f16x8*)(pb1 + kk);
    acc[0][0] = __builtin_amdgcn_mfma_f32_16x16x32_f16(a0, b0, acc[0][0], 0, 0, 0);
    acc[0][1] = __builtin_amdgcn_mfma_f32_16x16x32_f16(a0, b1, acc[0][1], 0, 0, 0);
    acc[1][0] = __builtin_amdgcn_mfma_f32_16x16x32_f16(a1, b0, acc[1][0], 0, 0, 0);
    acc[1][1] = __builtin_amdgcn_mfma_f32_16x16x32_f16(a1, b1, acc[1][1], 0, 0, 0);
  }
  // epilogue: bias add, fp16 via LDS transpose; optional register-space stats
  __syncthreads();
  f16* Cs = (f16*)&As[0][0];  // 64 x 72 tile (reuses As)
  float st_s[2] = {0.f, 0.f}, st_q[2] = {0.f, 0.f};
#pragma unroll
  for (int ni = 0; ni < 2; ++ni) {
    int nl = wn + ni * 16 + l15;
    float bv = bias[n0 + nl];
#pragma unroll
    for (int mi = 0; mi < 2; ++mi)
#pragma unroll
      for (int r = 0; r < 4; ++r) {
        f16 hv = (f16)(acc[mi][ni][r] + bv);
        Cs[(wm + mi * 16 + quad * 4 + r) * 72 + nl] = hv;
        if (statsout) {
          int gm = m0 + wm + mi * 16 + quad * 4 + r;
          float xv = (gm < M) ? (float)hv : 0.f;
          st_s[ni] += xv;
          st_q[ni] += xv * xv;
        }
      }
  }
  if (statsout) {
    float* bp = statsout + (blockIdx.y & 7) * 512;
#pragma unroll
    for (int ni = 0; ni < 2; ++ni) {
      float s = st_s[ni], q = st_q[ni];
      s += __shfl_xor(s, 16); q += __shfl_xor(q, 16);
      s += __shfl_xor(s, 32); q += __shfl_xor(q, 32);
      if (quad == 0) {
        int col = n0 + wn + ni * 16 + l15;
        atomicAdd(&bp[col], s);
        atomicAdd(&bp[256 + col], q);
      }
    }
  }
  __syncthreads();
  {
    int row = tid >> 2, c4 = (tid & 3) * 16;
    int gm = m0 + row;
    if (gm < M) {
      f16x8 v0 = *(const f16x8*)(&Cs[row * 72 + c4]);
      f16x8 v1 = *(const f16x8*)(&Cs[row * 72 + c4 + 8]);
      *(f16x8*)(out + (size_t)gm * OS + n0 + c4) = v0;
      *(f16x8*)(out + (size_t)gm * OS + n0 + c4 + 8) = v1;
    }
  }
}

// ---- Fused GATv2 + BN stats: wave/node, batch-4 edges (R13 best variant) ----
__global__ __launch_bounds__(256) void gat_fused(const f16* __restrict__ hxlr,
                                                 const float* __restrict__ eap,
                                                 const int* __restrict__ srcp,
                                                 const int* __restrict__ rowptr,
                                                 const float* __restrict__ We_t,
                                                 const float* __restrict__ att_t,
                                                 const float* __restrict__ cb_t,
                                                 f16* __restrict__ outb,
                                                 float* __restrict__ bns) {
  __shared__ float ls[2048];  // [wave][sum 256 | sumsq 256]
  int wave = threadIdx.x >> 6, lane = threadIdx.x & 63;
  int i = blockIdx.x * 4 + wave;  // 2500 * 4 == Nn exactly
  int ch = lane * 4;  // lane owns flat channels [ch, ch+4); head = lane>>3
  float we[9][4];
#pragma unroll
  for (int k = 0; k < 9; ++k) {
    float4 w4 = *(const float4*)(We_t + k * 256 + ch);
    we[k][0] = w4.x; we[k][1] = w4.y; we[k][2] = w4.z; we[k][3] = w4.w;
  }
  float4 a4 = *(const float4*)(att_t + ch);
  float att[4] = {a4.x, a4.y, a4.z, a4.w};
  f16x4 xr4 = *(const f16x4*)(hxlr + (size_t)i * 512 + 256 + ch);
  float xri[4] = {(float)xr4[0], (float)xr4[1], (float)xr4[2], (float)xr4[3]};
  float acc[4] = {0.f, 0.f, 0.f, 0.f};
  float d = 0.f;
  int r0 = rowptr[i], r1 = rowptr[i + 1];
  for (int base = r0; base < r1; base += 4) {
    int cnt = r1 - base;  // >= 1
    int ib[4];
#pragma unroll
    for (int b = 0; b < 4; ++b) ib[b] = base + (b < cnt ? b : cnt - 1);
    int js[4];
#pragma unroll
    for (int b = 0; b < 4; ++b) js[b] = srcp[ib[b]];
    float xlv[4][4];
#pragma unroll
    for (int b = 0; b < 4; ++b) {
      f16x4 v4 = *(const f16x4*)(hxlr + (size_t)js[b] * 512 + ch);
      xlv[b][0] = (float)v4[0]; xlv[b][1] = (float)v4[1];
      xlv[b][2] = (float)v4[2]; xlv[b][3] = (float)v4[3];
    }
    float sp[4];
#pragma unroll
    for (int b = 0; b < 4; ++b) {
      const float* ep = eap + (size_t)ib[b] * 12;
      float4 e0 = *(const float4*)ep;
      float4 e1 = *(const float4*)(ep + 4);
      float e8 = ep[8];
      float s = 0.f;
#pragma unroll
      for (int c = 0; c < 4; ++c) {
        float v = xlv[b][c] + xri[c];
        v += e0.x * we[0][c] + e0.y * we[1][c] + e0.z * we[2][c] + e0.w * we[3][c];
        v += e1.x * we[4][c] + e1.y * we[5][c] + e1.z * we[6][c] + e1.w * we[7][c];
        v += e8 * we[8][c];
        v = v > 0.f ? v : 0.2f * v;  // leaky_relu 0.2
        s += att[c] * v;
      }
      sp[b] = s;
    }
#pragma unroll
    for (int b = 0; b < 4; ++b) {
      sp[b] += __shfl_xor(sp[b], 1);
      sp[b] += __shfl_xor(sp[b], 2);
      sp[b] += __shfl_xor(sp[b], 4);
    }
#pragma unroll
    for (int b = 0; b < 4; ++b) {
      float z = (b < cnt) ? __expf(fminf(sp[b], 75.f)) : 0.f;
      d += z;
#pragma unroll
      for (int c = 0; c < 4; ++c) acc[c] += z * xlv[b][c];
    }
  }
  float inv = 1.f / (d + 1e-16f);  // empty node -> bias only (matches ref)
  float4 cb4 = *(const float4*)(cb_t + ch);
  f16x4 o;
  o[0] = (f16)(acc[0] * inv + cb4.x);
  o[1] = (f16)(acc[1] * inv + cb4.y);
  o[2] = (f16)(acc[2] * inv + cb4.z);
  o[3] = (f16)(acc[3] * inv + cb4.w);
  *(f16x4*)(outb + (size_t)i * 256 + ch) = o;
  // fused BN stats on the f16-rounded output
#pragma unroll
  for (int c = 0; c < 4; ++c) {
    float xv = (float)o[c];
    ls[wave * 512 + ch + c] = xv;
    ls[wave * 512 + 256 + ch + c] = xv * xv;
  }
  __syncthreads();
  float* bp = bns + (blockIdx.x & 7) * 512;  // 8-way partials: contention /8
  for (int q = threadIdx.x; q < 512; q += 256) {
    float sv = ls[q] + ls[512 + q] + ls[1024 + q] + ls[1536 + q];
    atomicAdd(&bp[q], sv);
  }
}

// ---------------- final: BN(pbn2)+ReLU folded, 256 -> 3 projection ----------------
__global__ __launch_bounds__(256) void final_kernel(const f16* __restrict__ hq,
                                                    const float* __restrict__ sums,
                                                    const float* __restrict__ gamma,
                                                    const float* __restrict__ beta,
                                                    const float* __restrict__ W,
                                                    const float* __restrict__ b,
                                                    float* __restrict__ out3) {
  int wave = threadIdx.x >> 6, lane = threadIdx.x & 63;
  int n = blockIdx.x * 4 + wave;
  if (n >= Nn) return;
  int ch = lane * 4;
  float su_[4] = {0.f, 0.f, 0.f, 0.f}, sq_[4] = {0.f, 0.f, 0.f, 0.f};
#pragma unroll
  for (int p = 0; p < 8; ++p) {
    float4 su = *(const float4*)(sums + p * 512 + ch);
    float4 sq = *(const float4*)(sums + p * 512 + 256 + ch);
    su_[0] += su.x; su_[1] += su.y; su_[2] += su.z; su_[3] += su.w;
    sq_[0] += sq.x; sq_[1] += sq.y; sq_[2] += sq.z; sq_[3] += sq.w;
  }
  float4 g4 = *(const float4*)(gamma + ch);
  float4 b4 = *(const float4*)(beta + ch);
  float g_[4] = {g4.x, g4.y, g4.z, g4.w};
  float bb_[4] = {b4.x, b4.y, b4.z, b4.w};
  f16x4 h4 = *(const f16x4*)(hq + (size_t)n * 256 + ch);
  float s0 = 0.f, s1 = 0.f, s2 = 0.f;
#pragma unroll
  for (int c = 0; c < 4; ++c) {
    float mu = su_[c] * (1.f / Nn);
    float var = fmaxf(sq_[c] * (1.f / Nn) - mu * mu, 0.f);
    float is = rsqrtf(var + 1e-5f) * g_[c];
    float y = fmaxf(((float)h4[c] - mu) * is + bb_[c], 0.f);
    const float* w = W + (ch + c) * 3;
    s0 += y * w[0]; s1 += y * w[1]; s2 += y * w[2];
  }
  for (int off = 1; off < 64; off <<= 1) {
    s0 += __shfl_xor(s0, off);
    s1 += __shfl_xor(s1, off);
    s2 += __shfl_xor(s2, off);
  }
  if (lane == 0) {
    out3[n * 3 + 0] = s0 + b[0];
    out3[n * 3 + 1] = s1 + b[1];
    out3[n * 3 + 2] = s2 + b[2];
  }
}

extern "C" void kernel_launch(void* const* d_in, const int* in_sizes, int n_in,
                              void* d_out, int out_size, void* d_ws, size_t ws_size,
                              hipStream_t stream) {
  const float* x         = (const float*)d_in[0];
  const float* edge_attr = (const float*)d_in[1];
  const int*   eidx      = (const int*)d_in[2];
  const float* lift_W    = (const float*)d_in[3];
  const float* lift_b    = (const float*)d_in[4];
  const float* Wl        = (const float*)d_in[5];
  const float* bl        = (const float*)d_in[6];
  const float* Wr        = (const float*)d_in[7];
  const float* br        = (const float*)d_in[8];
  const float* We        = (const float*)d_in[9];
  const float* att       = (const float*)d_in[10];
  const float* conv_b    = (const float*)d_in[11];
  const float* bn_g      = (const float*)d_in[12];
  const float* bn_b      = (const float*)d_in[13];
  const float* p1_W      = (const float*)d_in[14];
  const float* p1_b      = (const float*)d_in[15];
  const float* pbn1_g    = (const float*)d_in[16];
  const float* pbn1_b    = (const float*)d_in[17];
  const float* p2_W      = (const float*)d_in[18];
  const float* p2_b      = (const float*)d_in[19];
  const float* pbn2_g    = (const float*)d_in[20];
  const float* pbn2_b    = (const float*)d_in[21];
  const float* p3_W      = (const float*)d_in[22];
  const float* p3_b      = (const float*)d_in[23];
  const int* srcI = eidx;
  const int* dstI = eidx + Ee;

  char* wp = (char*)d_ws;
  auto carve = [&](size_t bytes) -> void* {
    void* p = (void*)wp;
    wp += (bytes + 255) & ~(size_t)255;
    return p;
  };
  // zero region: cstats(32) + bnsA(7 sets x 8 partials x 512) + deg(Nn)
  char*  zr     = (char*)carve((size_t)(32 + 7 * 4096 + Nn) * 4);
  float* cstats = (float*)zr;
  float* bnsA   = (float*)(zr + 32 * 4);
  int*   deg    = (int*)(zr + (32 + 7 * 4096) * 4);
  float* eap    = (float*)carve((size_t)Ee * 12 * sizeof(float));
  f16*   h16    = (f16*)carve((size_t)Nn * 256 * sizeof(f16));
  f16*   w16t   = (f16*)carve((size_t)786432 * sizeof(f16));
  float* biascat= (float*)carve((size_t)2560 * sizeof(float));
  f16*   hxlr   = (f16*)carve((size_t)Nn * 512 * sizeof(f16));
  f16*   outb16 = (f16*)carve((size_t)Nn * 256 * sizeof(f16));
  int*   rowptr = (int*)carve((size_t)(Nn + 1) * sizeof(int));
  int*   cursor = (int*)carve((size_t)Nn * sizeof(int));
  int*   srcp   = (int*)carve((size_t)Ee * sizeof(int));

  hipMemsetAsync(zr, 0, (size_t)(32 + 7 * 4096 + Nn) * 4, stream);

  prep_kernel<<<64 + (Ee + 255) / 256, 256, 0, stream>>>(edge_attr, dstI, cstats, deg);
  lift_kernel<<<Nn, 256, 0, stream>>>(x, lift_W, lift_b, h16);
  scan_kernel<<<1, 1024, 0, stream>>>(deg, rowptr, cursor);
  fill_eaperm_kernel<<<(Ee + 255) / 256, 256, 0, stream>>>(edge_attr, cstats, srcI, dstI,
                                                           cursor, srcp, eap);
  convert_kernel<<<dim3(512, 8), 256, 0, stream>>>(Wl, Wr, p1_W, p2_W, bl, br, w16t, biascat);

  const int MB = (Nn + 63) / 64;  // 157
  for (int t = 0; t < Tt; ++t) {
    const f16* Ain = (t == 0) ? h16 : outb16;
    const float* sums = (t == 0) ? nullptr : bnsA + (size_t)(t - 1) * 4096;
    int act = (t == 0) ? -1 : 0;
    gemm16_kernel<<<dim3(8, MB), 256, 0, stream>>>(Ain, w16t + (size_t)t * 131072,
                                                   biascat + t * 512, sums,
                                                   bn_g + (t > 0 ? (t - 1) * 256 : 0),
                                                   bn_b + (t > 0 ? (t - 1) * 256 : 0),
                                                   act, hxlr, Nn, 512, nullptr);
    gat_fused<<<2500, 256, 0, stream>>>(hxlr, eap, srcp, rowptr,
                                        We + t * 9 * 256, att + t * 256,
                                        conv_b + t * 256, outb16,
                                        bnsA + (size_t)t * 4096);
  }
  // projection head: BN folds in A-staging; output stats fused in gemm epilogue
  f16* pA = hxlr;                    // Nn*256
  f16* pB = hxlr + (size_t)Nn * 256; // Nn*256
  gemm16_kernel<<<dim3(4, MB), 256, 0, stream>>>(outb16, w16t + 655360, p1_b,
                                                 bnsA + 4 * 4096, bn_g + 4 * 256, bn_b + 4 * 256,
                                                 0, pA, Nn, 256, bnsA + 5 * 4096);
  gemm16_kernel<<<dim3(4, MB), 256, 0, stream>>>(pA, w16t + 720896, p2_b,
                                                 bnsA + 5 * 4096, pbn1_g, pbn1_b,
                                                 1, pB, Nn, 256, bnsA + 6 * 4096);
  final_kernel<<<2500, 256, 0, stream>>>(pB, bnsA + 6 * 4096, pbn2_g, pbn2_b, p3_W, p3_b,
                                         (float*)d_out);
}

// Round 18
// 559.840 us; speedup vs baseline: 1.1308x; 1.0178x over previous
//
#include <hip/hip_runtime.h>

#define Nn 10000
#define Ee 160000
#define HID 256
#define EDIM 9
#define INDIM 10
#define Tt 5

typedef _Float16 f16;
typedef _Float16 f16x8 __attribute__((ext_vector_type(8)));
typedef _Float16 f16x4 __attribute__((ext_vector_type(4)));
typedef float f32x4 __attribute__((ext_vector_type(4)));

// ---- mega-prologue: three independent jobs on disjoint block ranges ----
// blocks [0,64):        edge-attr column stats
// blocks [64,689):      degree histogram
// blocks [689,10689):   lift  h = relu(x @ lift_W + b) -> f16
// blocks [10689,14785): weight convert fp32->fp16 transposed + bias concat
__global__ __launch_bounds__(256) void prologue_kernel(
    const float* __restrict__ edge_attr, const int* __restrict__ dst,
    float* __restrict__ cs, int* __restrict__ deg,
    const float* __restrict__ x, const float* __restrict__ lift_W,
    const float* __restrict__ lift_b, f16* __restrict__ hq,
    const float* __restrict__ Wl, const float* __restrict__ Wr,
    const float* __restrict__ p1, const float* __restrict__ p2,
    const float* __restrict__ bl, const float* __restrict__ br,
    f16* __restrict__ wt, float* __restrict__ biascat) {
  const int blk = blockIdx.x;
  if (blk < 64) {
    float s[9], s2[9];
#pragma unroll
    for (int k = 0; k < 9; ++k) { s[k] = 0.f; s2[k] = 0.f; }
    for (int i = blk * 256 + threadIdx.x; i < Ee; i += 64 * 256) {
#pragma unroll
      for (int k = 0; k < 9; ++k) {
        float v = edge_attr[i * 9 + k];
        s[k] += v; s2[k] += v * v;
      }
    }
#pragma unroll
    for (int k = 0; k < 9; ++k) {
      for (int off = 1; off < 64; off <<= 1) {
        s[k] += __shfl_xor(s[k], off);
        s2[k] += __shfl_xor(s2[k], off);
      }
    }
    if ((threadIdx.x & 63) == 0) {
#pragma unroll
      for (int k = 0; k < 9; ++k) {
        atomicAdd(&cs[k], s[k]);
        atomicAdd(&cs[16 + k], s2[k]);
      }
    }
  } else if (blk < 689) {
    int e = (blk - 64) * 256 + threadIdx.x;
    if (e < Ee) atomicAdd(&deg[dst[e]], 1);
  } else if (blk < 10689) {
    __shared__ float xs[INDIM];
    int n = blk - 689, ch = threadIdx.x;
    if (ch < INDIM) xs[ch] = x[n * INDIM + ch];
    __syncthreads();
    float s = lift_b[ch];
#pragma unroll
    for (int k = 0; k < INDIM; ++k) s += xs[k] * lift_W[k * 256 + ch];
    hq[n * 256 + ch] = (f16)fmaxf(s, 0.f);
  } else {
    int idx = blk - 10689;              // 0..4095
    int nrow = idx & 511, sl = idx >> 9;  // 512 x 8
    int k = threadIdx.x;
    if (sl == 7) {
      int flat = nrow * 256 + k;
      if (flat < 2560) {
        int t = flat >> 9, c = flat & 511;
        biascat[flat] = (c < 256) ? bl[t * 256 + c] : br[t * 256 + c - 256];
      }
      return;
    }
    const float* srcp; int n = nrow; size_t dstoff;
    if (sl < 5) {
      dstoff = (size_t)sl * 131072 + (size_t)nrow * 256 + k;
      if (nrow < 256) srcp = Wl + sl * 65536;
      else { srcp = Wr + sl * 65536; n = nrow - 256; }
    } else {
      if (nrow >= 256) return;
      dstoff = 655360 + (size_t)(sl - 5) * 65536 + (size_t)nrow * 256 + k;
      srcp = (sl == 5) ? p1 : p2;
    }
    wt[dstoff] = (f16)srcp[k * 256 + n];
  }
}

// ---------------- CSR rowptr scan (single block) ----------------
__global__ __launch_bounds__(1024) void scan_kernel(const int* __restrict__ deg,
                                                    int* __restrict__ rowptr,
                                                    int* __restrict__ cursor) {
  __shared__ int part[1024];
  int tid = threadIdx.x;
  const int CH = (Nn + 1023) / 1024;
  int start = tid * CH;
  int s = 0;
  for (int i = 0; i < CH; ++i) { int idx = start + i; if (idx < Nn) s += deg[idx]; }
  part[tid] = s;
  __syncthreads();
  for (int off = 1; off < 1024; off <<= 1) {
    int v = part[tid];
    int w = (tid >= off) ? part[tid - off] : 0;
    __syncthreads();
    part[tid] = v + w;
    __syncthreads();
  }
  int run = part[tid] - s;  // exclusive prefix
  for (int i = 0; i < CH; ++i) {
    int idx = start + i;
    if (idx < Nn) { rowptr[idx] = run; cursor[idx] = run; run += deg[idx]; }
  }
  if (tid == 0) rowptr[Nn] = Ee;
}

// ---- fused CSR fill + src permute + edge-attr normalize (f32, stride 12) ----
__global__ __launch_bounds__(256) void fill_eaperm_kernel(const float* __restrict__ edge_attr,
                                                          const float* __restrict__ cs,
                                                          const int* __restrict__ srcIn,
                                                          const int* __restrict__ dstIn,
                                                          int* __restrict__ cursor,
                                                          int* __restrict__ srcp,
                                                          float* __restrict__ eap) {
  int e = blockIdx.x * 256 + threadIdx.x;
  if (e >= Ee) return;
  int pos = atomicAdd(&cursor[dstIn[e]], 1);
  srcp[pos] = srcIn[e];
  const float* a = edge_attr + e * 9;
  float o[12];
#pragma unroll
  for (int k = 0; k < 9; ++k) {
    float mu = cs[k] * (1.f / Ee);
    float var = fmaxf(cs[16 + k] * (1.f / Ee) - mu * mu, 0.f);
    o[k] = (a[k] - mu) / (sqrtf(var) + 1e-8f);
  }
  o[9] = o[10] = o[11] = 0.f;
  float4 v0 = {o[0], o[1], o[2], o[3]};
  float4 v1 = {o[4], o[5], o[6], o[7]};
  float4 v2 = {o[8], o[9], o[10], o[11]};
  *(float4*)(eap + (size_t)pos * 12 + 0) = v0;
  *(float4*)(eap + (size_t)pos * 12 + 4) = v1;
  *(float4*)(eap + (size_t)pos * 12 + 8) = v2;
}

// ------------- fp16 MFMA GEMM: A staged in LDS, B streamed from L2 -------------
// statsout != nullptr: fused BN stats of the f16-rounded output via register
// reduction (shfl over quad lanes) into 8-way partial buffers.
__global__ __launch_bounds__(256) void gemm16_kernel(const f16* __restrict__ A,
                                                     const f16* __restrict__ BT,
                                                     const float* __restrict__ bias,
                                                     const float* __restrict__ sums,
                                                     const float* __restrict__ gamma,
                                                     const float* __restrict__ beta,
                                                     int act,
                                                     f16* __restrict__ out,
                                                     int M, int OS,
                                                     float* __restrict__ statsout) {
  __shared__ __align__(16) f16 As[64][264];
  const int tid = threadIdx.x;
  const int wave = tid >> 6, lane = tid & 63;
  const int l15 = lane & 15, quad = lane >> 4;
  const int m0 = blockIdx.y * 64, n0 = blockIdx.x * 64;
  const int wm = (wave >> 1) * 32, wn = (wave & 1) * 32;
  const int colbase = (tid & 31) * 8, rowbase = tid >> 5;
  float sA[8], tA[8];
  if (act >= 0) {
#pragma unroll
    for (int c4 = 0; c4 < 2; ++c4) {
      float su_[4] = {0.f, 0.f, 0.f, 0.f}, sq_[4] = {0.f, 0.f, 0.f, 0.f};
#pragma unroll
      for (int p = 0; p < 8; ++p) {
        float4 su = *(const float4*)(sums + p * 512 + colbase + c4 * 4);
        float4 sq = *(const float4*)(sums + p * 512 + 256 + colbase + c4 * 4);
        su_[0] += su.x; su_[1] += su.y; su_[2] += su.z; su_[3] += su.w;
        sq_[0] += sq.x; sq_[1] += sq.y; sq_[2] += sq.z; sq_[3] += sq.w;
      }
      float4 g4 = *(const float4*)(gamma + colbase + c4 * 4);
      float4 b4 = *(const float4*)(beta + colbase + c4 * 4);
      float g_[4] = {g4.x, g4.y, g4.z, g4.w};
      float b_[4] = {b4.x, b4.y, b4.z, b4.w};
#pragma unroll
      for (int c = 0; c < 4; ++c) {
        float mu = su_[c] * (1.f / Nn);
        float var = fmaxf(sq_[c] * (1.f / Nn) - mu * mu, 0.f);
        float is = rsqrtf(var + 1e-5f) * g_[c];
        sA[c4 * 4 + c] = is;
        tA[c4 * 4 + c] = b_[c] - mu * is;
      }
    }
  }
  // stage A panel (64x256) only: 8 x 16B chunks per thread
#pragma unroll
  for (int i = 0; i < 8; ++i) {
    int c = tid + 256 * i;
    int row = c >> 5, col = (c & 31) * 8;
    f16x8 av = {};
    int gm = m0 + row;
    if (gm < M) av = *(const f16x8*)(A + (size_t)gm * 256 + col);
    if (act >= 0) {
#pragma unroll
      for (int e = 0; e < 8; ++e) {
        float y = (float)av[e] * sA[e] + tA[e];
        if (act == 0) y = y > 0.f ? y : (__expf(y) - 1.f);
        else y = fmaxf(y, 0.f);
        av[e] = (f16)y;
      }
    }
    *(f16x8*)(&As[row][col]) = av;
  }
  __syncthreads();
  const f16* pb0 = BT + (size_t)(n0 + wn + l15) * 256 + quad * 8;
  const f16* pb1 = BT + (size_t)(n0 + wn + 16 + l15) * 256 + quad * 8;
  f32x4 zero4 = {0.f, 0.f, 0.f, 0.f};
  f32x4 acc[2][2] = {{zero4, zero4}, {zero4, zero4}};
#pragma unroll
  for (int kk = 0; kk < 256; kk += 32) {
    f16x8 a0 = *(const f16x8*)(&As[wm + l15][kk + quad * 8]);
    f16x8 a1 = *(const f16x8*)(&As[wm + 16 + l15][kk + quad * 8]);
    f16x8 b0 = *(const f16x8*)(pb0 + kk);
    f16x8 b1 = *(const f16x8*)(pb1 + kk);
    acc[0][0] = __builtin_amdgcn_mfma_f32_16x16x32_f16(a0, b0, acc[0][0], 0, 0, 0);
    acc[0][1] = __builtin_amdgcn_mfma_f32_16x16x32_f16(a0, b1, acc[0][1], 0, 0, 0);
    acc[1][0] = __builtin_amdgcn_mfma_f32_16x16x32_f16(a1, b0, acc[1][0], 0, 0, 0);
    acc[1][1] = __builtin_amdgcn_mfma_f32_16x16x32_f16(a1, b1, acc[1][1], 0, 0, 0);
  }
  // epilogue: bias add, fp16 via LDS transpose; optional register-space stats
  __syncthreads();
  f16* Cs = (f16*)&As[0][0];  // 64 x 72 tile (reuses As)
  float st_s[2] = {0.f, 0.f}, st_q[2] = {0.f, 0.f};
#pragma unroll
  for (int ni = 0; ni < 2; ++ni) {
    int nl = wn + ni * 16 + l15;
    float bv = bias[n0 + nl];
#pragma unroll
    for (int mi = 0; mi < 2; ++mi)
#pragma unroll
      for (int r = 0; r < 4; ++r) {
        f16 hv = (f16)(acc[mi][ni][r] + bv);
        Cs[(wm + mi * 16 + quad * 4 + r) * 72 + nl] = hv;
        if (statsout) {
          int gm = m0 + wm + mi * 16 + quad * 4 + r;
          float xv = (gm < M) ? (float)hv : 0.f;
          st_s[ni] += xv;
          st_q[ni] += xv * xv;
        }
      }
  }
  if (statsout) {
    float* bp = statsout + (blockIdx.y & 7) * 512;
#pragma unroll
    for (int ni = 0; ni < 2; ++ni) {
      float s = st_s[ni], q = st_q[ni];
      s += __shfl_xor(s, 16); q += __shfl_xor(q, 16);
      s += __shfl_xor(s, 32); q += __shfl_xor(q, 32);
      if (quad == 0) {
        int col = n0 + wn + ni * 16 + l15;
        atomicAdd(&bp[col], s);
        atomicAdd(&bp[256 + col], q);
      }
    }
  }
  __syncthreads();
  {
    int row = tid >> 2, c4 = (tid & 3) * 16;
    int gm = m0 + row;
    if (gm < M) {
      f16x8 v0 = *(const f16x8*)(&Cs[row * 72 + c4]);
      f16x8 v1 = *(const f16x8*)(&Cs[row * 72 + c4 + 8]);
      *(f16x8*)(out + (size_t)gm * OS + n0 + c4) = v0;
      *(f16x8*)(out + (size_t)gm * OS + n0 + c4 + 8) = v1;
    }
  }
}

// ---- Fused GATv2 + BN stats: wave/node, batch-4 edges (converged variant) ----
__global__ __launch_bounds__(256) void gat_fused(const f16* __restrict__ hxlr,
                                                 const float* __restrict__ eap,
                                                 const int* __restrict__ srcp,
                                                 const int* __restrict__ rowptr,
                                                 const float* __restrict__ We_t,
                                                 const float* __restrict__ att_t,
                                                 const float* __restrict__ cb_t,
                                                 f16* __restrict__ outb,
                                                 float* __restrict__ bns) {
  __shared__ float ls[2048];  // [wave][sum 256 | sumsq 256]
  int wave = threadIdx.x >> 6, lane = threadIdx.x & 63;
  int i = blockIdx.x * 4 + wave;  // 2500 * 4 == Nn exactly
  int ch = lane * 4;  // lane owns flat channels [ch, ch+4); head = lane>>3
  float we[9][4];
#pragma unroll
  for (int k = 0; k < 9; ++k) {
    float4 w4 = *(const float4*)(We_t + k * 256 + ch);
    we[k][0] = w4.x; we[k][1] = w4.y; we[k][2] = w4.z; we[k][3] = w4.w;
  }
  float4 a4 = *(const float4*)(att_t + ch);
  float att[4] = {a4.x, a4.y, a4.z, a4.w};
  f16x4 xr4 = *(const f16x4*)(hxlr + (size_t)i * 512 + 256 + ch);
  float xri[4] = {(float)xr4[0], (float)xr4[1], (float)xr4[2], (float)xr4[3]};
  float acc[4] = {0.f, 0.f, 0.f, 0.f};
  float d = 0.f;
  int r0 = rowptr[i], r1 = rowptr[i + 1];
  for (int base = r0; base < r1; base += 4) {
    int cnt = r1 - base;  // >= 1
    int ib[4];
#pragma unroll
    for (int b = 0; b < 4; ++b) ib[b] = base + (b < cnt ? b : cnt - 1);
    int js[4];
#pragma unroll
    for (int b = 0; b < 4; ++b) js[b] = srcp[ib[b]];
    float xlv[4][4];
#pragma unroll
    for (int b = 0; b < 4; ++b) {
      f16x4 v4 = *(const f16x4*)(hxlr + (size_t)js[b] * 512 + ch);
      xlv[b][0] = (float)v4[0]; xlv[b][1] = (float)v4[1];
      xlv[b][2] = (float)v4[2]; xlv[b][3] = (float)v4[3];
    }
    float sp[4];
#pragma unroll
    for (int b = 0; b < 4; ++b) {
      const float* ep = eap + (size_t)ib[b] * 12;
      float4 e0 = *(const float4*)ep;
      float4 e1 = *(const float4*)(ep + 4);
      float e8 = ep[8];
      float s = 0.f;
#pragma unroll
      for (int c = 0; c < 4; ++c) {
        float v = xlv[b][c] + xri[c];
        v += e0.x * we[0][c] + e0.y * we[1][c] + e0.z * we[2][c] + e0.w * we[3][c];
        v += e1.x * we[4][c] + e1.y * we[5][c] + e1.z * we[6][c] + e1.w * we[7][c];
        v += e8 * we[8][c];
        v = v > 0.f ? v : 0.2f * v;  // leaky_relu 0.2
        s += att[c] * v;
      }
      sp[b] = s;
    }
#pragma unroll
    for (int b = 0; b < 4; ++b) {
      sp[b] += __shfl_xor(sp[b], 1);
      sp[b] += __shfl_xor(sp[b], 2);
      sp[b] += __shfl_xor(sp[b], 4);
    }
#pragma unroll
    for (int b = 0; b < 4; ++b) {
      float z = (b < cnt) ? __expf(fminf(sp[b], 75.f)) : 0.f;
      d += z;
#pragma unroll
      for (int c = 0; c < 4; ++c) acc[c] += z * xlv[b][c];
    }
  }
  float inv = 1.f / (d + 1e-16f);  // empty node -> bias only (matches ref)
  float4 cb4 = *(const float4*)(cb_t + ch);
  f16x4 o;
  o[0] = (f16)(acc[0] * inv + cb4.x);
  o[1] = (f16)(acc[1] * inv + cb4.y);
  o[2] = (f16)(acc[2] * inv + cb4.z);
  o[3] = (f16)(acc[3] * inv + cb4.w);
  *(f16x4*)(outb + (size_t)i * 256 + ch) = o;
  // fused BN stats on the f16-rounded output
#pragma unroll
  for (int c = 0; c < 4; ++c) {
    float xv = (float)o[c];
    ls[wave * 512 + ch + c] = xv;
    ls[wave * 512 + 256 + ch + c] = xv * xv;
  }
  __syncthreads();
  float* bp = bns + (blockIdx.x & 7) * 512;  // 8-way partials: contention /8
  for (int q = threadIdx.x; q < 512; q += 256) {
    float sv = ls[q] + ls[512 + q] + ls[1024 + q] + ls[1536 + q];
    atomicAdd(&bp[q], sv);
  }
}

// ---------------- final: BN(pbn2)+ReLU folded, 256 -> 3 projection ----------------
__global__ __launch_bounds__(256) void final_kernel(const f16* __restrict__ hq,
                                                    const float* __restrict__ sums,
                                                    const float* __restrict__ gamma,
                                                    const float* __restrict__ beta,
                                                    const float* __restrict__ W,
                                                    const float* __restrict__ b,
                                                    float* __restrict__ out3) {
  int wave = threadIdx.x >> 6, lane = threadIdx.x & 63;
  int n = blockIdx.x * 4 + wave;
  if (n >= Nn) return;
  int ch = lane * 4;
  float su_[4] = {0.f, 0.f, 0.f, 0.f}, sq_[4] = {0.f, 0.f, 0.f, 0.f};
#pragma unroll
  for (int p = 0; p < 8; ++p) {
    float4 su = *(const float4*)(sums + p * 512 + ch);
    float4 sq = *(const float4*)(sums + p * 512 + 256 + ch);
    su_[0] += su.x; su_[1] += su.y; su_[2] += su.z; su_[3] += su.w;
    sq_[0] += sq.x; sq_[1] += sq.y; sq_[2] += sq.z; sq_[3] += sq.w;
  }
  float4 g4 = *(const float4*)(gamma + ch);
  float4 b4 = *(const float4*)(beta + ch);
  float g_[4] = {g4.x, g4.y, g4.z, g4.w};
  float bb_[4] = {b4.x, b4.y, b4.z, b4.w};
  f16x4 h4 = *(const f16x4*)(hq + (size_t)n * 256 + ch);
  float s0 = 0.f, s1 = 0.f, s2 = 0.f;
#pragma unroll
  for (int c = 0; c < 4; ++c) {
    float mu = su_[c] * (1.f / Nn);
    float var = fmaxf(sq_[c] * (1.f / Nn) - mu * mu, 0.f);
    float is = rsqrtf(var + 1e-5f) * g_[c];
    float y = fmaxf(((float)h4[c] - mu) * is + bb_[c], 0.f);
    const float* w = W + (ch + c) * 3;
    s0 += y * w[0]; s1 += y * w[1]; s2 += y * w[2];
  }
  for (int off = 1; off < 64; off <<= 1) {
    s0 += __shfl_xor(s0, off);
    s1 += __shfl_xor(s1, off);
    s2 += __shfl_xor(s2, off);
  }
  if (lane == 0) {
    out3[n * 3 + 0] = s0 + b[0];
    out3[n * 3 + 1] = s1 + b[1];
    out3[n * 3 + 2] = s2 + b[2];
  }
}

extern "C" void kernel_launch(void* const* d_in, const int* in_sizes, int n_in,
                              void* d_out, int out_size, void* d_ws, size_t ws_size,
                              hipStream_t stream) {
  const float* x         = (const float*)d_in[0];
  const float* edge_attr = (const float*)d_in[1];
  const int*   eidx      = (const int*)d_in[2];
  const float* lift_W    = (const float*)d_in[3];
  const float* lift_b    = (const float*)d_in[4];
  const float* Wl        = (const float*)d_in[5];
  const float* bl        = (const float*)d_in[6];
  const float* Wr        = (const float*)d_in[7];
  const float* br        = (const float*)d_in[8];
  const float* We        = (const float*)d_in[9];
  const float* att       = (const float*)d_in[10];
  const float* conv_b    = (const float*)d_in[11];
  const float* bn_g      = (const float*)d_in[12];
  const float* bn_b      = (const float*)d_in[13];
  const float* p1_W      = (const float*)d_in[14];
  const float* p1_b      = (const float*)d_in[15];
  const float* pbn1_g    = (const float*)d_in[16];
  const float* pbn1_b    = (const float*)d_in[17];
  const float* p2_W      = (const float*)d_in[18];
  const float* p2_b      = (const float*)d_in[19];
  const float* pbn2_g    = (const float*)d_in[20];
  const float* pbn2_b    = (const float*)d_in[21];
  const float* p3_W      = (const float*)d_in[22];
  const float* p3_b      = (const float*)d_in[23];
  const int* srcI = eidx;
  const int* dstI = eidx + Ee;

  char* wp = (char*)d_ws;
  auto carve = [&](size_t bytes) -> void* {
    void* p = (void*)wp;
    wp += (bytes + 255) & ~(size_t)255;
    return p;
  };
  // zero region: cstats(32) + bnsA(7 sets x 8 partials x 512) + deg(Nn)
  char*  zr     = (char*)carve((size_t)(32 + 7 * 4096 + Nn) * 4);
  float* cstats = (float*)zr;
  float* bnsA   = (float*)(zr + 32 * 4);
  int*   deg    = (int*)(zr + (32 + 7 * 4096) * 4);
  float* eap    = (float*)carve((size_t)Ee * 12 * sizeof(float));
  f16*   h16    = (f16*)carve((size_t)Nn * 256 * sizeof(f16));
  f16*   w16t   = (f16*)carve((size_t)786432 * sizeof(f16));
  float* biascat= (float*)carve((size_t)2560 * sizeof(float));
  f16*   hxlr   = (f16*)carve((size_t)Nn * 512 * sizeof(f16));
  f16*   outb16 = (f16*)carve((size_t)Nn * 256 * sizeof(f16));
  int*   rowptr = (int*)carve((size_t)(Nn + 1) * sizeof(int));
  int*   cursor = (int*)carve((size_t)Nn * sizeof(int));
  int*   srcp   = (int*)carve((size_t)Ee * sizeof(int));

  hipMemsetAsync(zr, 0, (size_t)(32 + 7 * 4096 + Nn) * 4, stream);

  prologue_kernel<<<14785, 256, 0, stream>>>(edge_attr, dstI, cstats, deg,
                                             x, lift_W, lift_b, h16,
                                             Wl, Wr, p1_W, p2_W, bl, br, w16t, biascat);
  scan_kernel<<<1, 1024, 0, stream>>>(deg, rowptr, cursor);
  fill_eaperm_kernel<<<(Ee + 255) / 256, 256, 0, stream>>>(edge_attr, cstats, srcI, dstI,
                                                           cursor, srcp, eap);

  const int MB = (Nn + 63) / 64;  // 157
  for (int t = 0; t < Tt; ++t) {
    const f16* Ain = (t == 0) ? h16 : outb16;
    const float* sums = (t == 0) ? nullptr : bnsA + (size_t)(t - 1) * 4096;
    int act = (t == 0) ? -1 : 0;
    gemm16_kernel<<<dim3(8, MB), 256, 0, stream>>>(Ain, w16t + (size_t)t * 131072,
                                                   biascat + t * 512, sums,
                                                   bn_g + (t > 0 ? (t - 1) * 256 : 0),
                                                   bn_b + (t > 0 ? (t - 1) * 256 : 0),
                                                   act, hxlr, Nn, 512, nullptr);
    gat_fused<<<2500, 256, 0, stream>>>(hxlr, eap, srcp, rowptr,
                                        We + t * 9 * 256, att + t * 256,
                                        conv_b + t * 256, outb16,
                                        bnsA + (size_t)t * 4096);
  }
  // projection head: BN folds in A-staging; output stats fused in gemm epilogue
  f16* pA = hxlr;                    // Nn*256
  f16* pB = hxlr + (size_t)Nn * 256; // Nn*256
  gemm16_kernel<<<dim3(4, MB), 256, 0, stream>>>(outb16, w16t + 655360, p1_b,
                                                 bnsA + 4 * 4096, bn_g + 4 * 256, bn_b + 4 * 256,
                                                 0, pA, Nn, 256, bnsA + 5 * 4096);
  gemm16_kernel<<<dim3(4, MB), 256, 0, stream>>>(pA, w16t + 720896, p2_b,
                                                 bnsA + 5 * 4096, pbn1_g, pbn1_b,
                                                 1, pB, Nn, 256, bnsA + 6 * 4096);
  final_kernel<<<2500, 256, 0, stream>>>(pB, bnsA + 6 * 4096, pbn2_g, pbn2_b, p3_W, p3_b,
                                         (float*)d_out);
}